// Round 8
// baseline (303.390 us; speedup 1.0000x reference)
//
#include <hip/hip_runtime.h>

// Problem constants
#define Bsz 16
#define Nseq 784
#define DIM 512
#define NH 8
#define KD 64
#define VD 256
#define QKV_OUT 3072   // (2*64+256)*8
#define HV 2048        // NH*VD
#define NN 614656      // 784*784

typedef __attribute__((ext_vector_type(8))) short short8;
typedef __attribute__((ext_vector_type(4))) float floatx4;
typedef __attribute__((ext_vector_type(16))) float f32x16;
typedef __attribute__((ext_vector_type(4))) unsigned u32x4;

#define OSTR 136   // QK epilogue: [256 m][128 j] stride 136 -> 34816 shorts (=69632B smem)
#define VSTR 264   // V epilogue:  [128 ch][256 m] stride 264 -> 33792 shorts

#if __has_builtin(__builtin_amdgcn_exp2f)
#define EXP2(x) __builtin_amdgcn_exp2f(x)
#else
#define EXP2(x) exp2f(x)
#endif

__device__ __forceinline__ unsigned short f2bf(float f) {
  union { float f; unsigned u; } v; v.f = f;
  unsigned r = v.u + 0x7fffu + ((v.u >> 16) & 1u);
  return (unsigned short)(r >> 16);
}
__device__ __forceinline__ float bfLO(unsigned u) {
  union { unsigned u; float f; } v; v.u = u << 16; return v.f;
}
__device__ __forceinline__ float bfHI(unsigned u) {
  union { unsigned u; float f; } v; v.u = u & 0xffff0000u; return v.f;
}

// async global->LDS, 16B per lane; LDS dst = wave-uniform base + lane*16
__device__ __forceinline__ void glds16(const unsigned short* g, unsigned short* l) {
  __builtin_amdgcn_global_load_lds(
      (const __attribute__((address_space(1))) void*)g,
      (__attribute__((address_space(3))) void*)l, 16, 0, 0);
}

// ---------------- K0: fused fp32 -> bf16 convert (x, qkv_w, proj_w) ----------------
#define N4X 1605632   // x float4s
#define N4Q 393216    // qkv_w float4s
#define N4P 262144    // proj_w float4s
__global__ void cvt_all_kernel(const float* __restrict__ x,
                               const float* __restrict__ qw,
                               const float* __restrict__ pw,
                               unsigned short* __restrict__ xb,
                               unsigned short* __restrict__ wq,
                               unsigned short* __restrict__ wp) {
  int i = blockIdx.x * 256 + threadIdx.x;
  const float4* s; ushort4* d; int off;
  if (i < N4X)              { s = (const float4*)x;  d = (ushort4*)xb; off = i; }
  else if (i < N4X + N4Q)   { s = (const float4*)qw; d = (ushort4*)wq; off = i - N4X; }
  else if (i < N4X + N4Q + N4P) { s = (const float4*)pw; d = (ushort4*)wp; off = i - N4X - N4Q; }
  else return;
  float4 v = s[off];
  ushort4 o;
  o.x = f2bf(v.x); o.y = f2bf(v.y); o.z = f2bf(v.z); o.w = f2bf(v.w);
  d[off] = o;
}

// ---------------- K0b: bias table [8][784][784] bf16, log2e-folded, columns bit2<->bit3 permuted ----------------
__global__ void bias_pre_kernel(const float* __restrict__ biases,
                                const int* __restrict__ bias_idxs,
                                unsigned short* __restrict__ bias_tab) {
  int t = blockIdx.x * 256 + threadIdx.x;
  if (t >= NN) return;
  int idx = bias_idxs[t];
  // 784 % 16 == 0, so swapping bits 2,3 of the flat index permutes within the column part
  int p = (t & ~12) | ((t & 4) << 1) | ((t & 8) >> 1);
  for (int h = 0; h < NH; ++h)
    bias_tab[(size_t)h * NN + p] = f2bf(1.44269504f * biases[h * Nseq + idx]);
}

// ---------------- K1: QKV GEMM, 256x128 tile / 4 waves / wave-tile 128x64 ----------------
// LDS-wall cut vs 128^2: reads/MFMA 0.5 -> 0.375, 2 barriers per 32 (not 16) MFMAs/wave,
// staging writes per unit work -25%. LDS 69.6KB -> 2 blocks/CU (occupancy proven non-binding
// R6/R7). Staging: As[2][8192] + Bs[2][4096] shorts (48KB) inside the 69.6KB epilogue arena.
__global__ __launch_bounds__(256, 2) void qkv_gemm_kernel(
    const unsigned short* __restrict__ A,
    const unsigned short* __restrict__ Bw,
    const float* __restrict__ gamma, const float* __restrict__ beta,
    const float* __restrict__ mean,  const float* __restrict__ var,
    unsigned short* __restrict__ qo,   // [B,H,N,64] (pre-scaled by 0.125*log2e)
    unsigned short* __restrict__ ko,   // [B,H,N,64]
    unsigned short* __restrict__ vto)  // [B,H,256,N] with n-dim bit2<->bit3 permuted
{
  const int K = DIM;
  __shared__ unsigned short smem[256 * OSTR];  // 69632B
  int tid = threadIdx.x;
  int wave = tid >> 6, lane = tid & 63;
  int quad = lane >> 4, l16 = lane & 15;
  int wm = wave >> 1, wn = wave & 1;
  // XCD-chunked bijective swizzle: 1176 = 8 * 147
  int bid = blockIdx.x;
  int wgid = (bid & 7) * 147 + (bid >> 3);
  int m0 = (wgid / 24) * 256, n0 = (wgid % 24) * 128;

  // staging source: thread t stages row (sweep*64 + wave*16 + lane/4), 16B chunk (lane&3)
  int srow = wave * 16 + (lane >> 2);
  int sch = (lane & 3) * 8;
  const unsigned short* Ab = A + (size_t)(m0 + srow) * K + sch;   // + s*64*K per sweep
  const unsigned short* Bb = Bw + (size_t)(n0 + srow) * K + sch;  // + s*64*K per sweep
  unsigned short* AsW = &smem[wave * 512];            // + s*2048 per sweep, + buf*8192
  unsigned short* BsW = &smem[16384 + wave * 512];    // + s*2048 per sweep, + buf*4096

  floatx4 acc[8][4];
  for (int i = 0; i < 8; ++i)
    for (int j = 0; j < 4; ++j) acc[i][j] = (floatx4)0.0f;

  // prologue: stage k-step 0 into buf 0 (6 glds: 4 A sweeps + 2 B sweeps)
#pragma unroll
  for (int s = 0; s < 4; ++s) glds16(Ab + s * 64 * K, AsW + s * 2048);
#pragma unroll
  for (int s = 0; s < 2; ++s) glds16(Bb + s * 64 * K, BsW + s * 2048);

  for (int k = 0; k < 16; ++k) {
    int cur = k & 1, nb = cur ^ 1;
    __builtin_amdgcn_s_waitcnt(0xC07F);   // lgkmcnt(0) only
    __builtin_amdgcn_s_barrier();
    int k0n = ((k + 1) & 15) * 32;        // wrap keeps vmcnt uniform
#pragma unroll
    for (int s = 0; s < 4; ++s) glds16(Ab + k0n + s * 64 * K, AsW + nb * 8192 + s * 2048);
#pragma unroll
    for (int s = 0; s < 2; ++s) glds16(Bb + k0n + s * 64 * K, BsW + nb * 4096 + s * 2048);
    __builtin_amdgcn_s_waitcnt(0x0F76);   // vmcnt(6): this k landed, k+1 in flight
    __builtin_amdgcn_s_barrier();

    const unsigned short* As = &smem[cur * 8192];
    const unsigned short* Bs = &smem[16384 + cur * 4096];
    short8 af[8], bfr[4];
#pragma unroll
    for (int mt = 0; mt < 8; ++mt)
      af[mt] = *(const short8*)&As[(wm * 128 + mt * 16 + l16) * 32 + quad * 8];
#pragma unroll
    for (int nt = 0; nt < 4; ++nt)
      bfr[nt] = *(const short8*)&Bs[(wn * 64 + nt * 16 + l16) * 32 + quad * 8];
#pragma unroll
    for (int mt = 0; mt < 8; ++mt)
#pragma unroll
      for (int nt = 0; nt < 4; ++nt)
        acc[mt][nt] = __builtin_amdgcn_mfma_f32_16x16x32_bf16(af[mt], bfr[nt], acc[mt][nt], 0, 0, 0);
  }

  int tt = n0 % 384;        // 0 => QK tile; 128/256 => V tile
  int h = n0 / 384;
  __builtin_amdgcn_s_waitcnt(0x0070);   // drain wrapped prefetch before smem reuse
  __syncthreads();

  if (tt == 0) {
    for (int nt = 0; nt < 4; ++nt) {
      int o = n0 + wn * 64 + nt * 16 + l16;
      float sc = gamma[o] * rsqrtf(var[o] + 1e-5f);
      float bb = beta[o] - mean[o] * sc;
      if (wn == 0) { sc *= 0.18033688f; bb *= 0.18033688f; }  // 0.125 * log2e folded into Q
      int jl = wn * 64 + nt * 16 + l16;
      for (int mt = 0; mt < 8; ++mt)
        for (int r = 0; r < 4; ++r) {
          int ml = wm * 128 + mt * 16 + quad * 4 + r;
          smem[ml * OSTR + jl] = f2bf(acc[mt][nt][r] * sc + bb);
        }
    }
    __syncthreads();
    for (int i = 0; i < 16; ++i) {
      int c = i * 256 + tid;
      int ml = c >> 4, jc = c & 15;
      int m = m0 + ml;
      int b = m / 784, n = m - b * 784;
      uint4 v = *(uint4*)&smem[ml * OSTR + jc * 8];
      int j = jc * 8;
      if (j < 64) *(uint4*)&qo[(((size_t)b * NH + h) * Nseq + n) * KD + j] = v;
      else        *(uint4*)&ko[(((size_t)b * NH + h) * Nseq + n) * KD + (j - 64)] = v;
    }
  } else {
    for (int nt = 0; nt < 4; ++nt) {
      int o = n0 + wn * 64 + nt * 16 + l16;
      float sc = gamma[o] * rsqrtf(var[o] + 1e-5f);
      float bb = beta[o] - mean[o] * sc;
      int cl = wn * 64 + nt * 16 + l16;
      // kv bit2<->bit3 permutation folded into the write index; 4 r-values are
      // contiguous in m -> pack into one 8B LDS store.
      int qperm = (quad & 1) * 8 + (quad >> 1) * 4;
      for (int mt = 0; mt < 8; ++mt) {
        int ml0 = wm * 128 + mt * 16 + qperm;
        ushort4 pk;
        pk.x = f2bf(acc[mt][nt][0] * sc + bb);
        pk.y = f2bf(acc[mt][nt][1] * sc + bb);
        pk.z = f2bf(acc[mt][nt][2] * sc + bb);
        pk.w = f2bf(acc[mt][nt][3] * sc + bb);
        *(ushort4*)&smem[cl * VSTR + ml0] = pk;
      }
    }
    __syncthreads();
    int cbase = tt - 128;
    for (int i = 0; i < 16; ++i) {
      int c = i * 256 + tid;
      int cl = c >> 5, mc = c & 31;
      int m = m0 + mc * 8;
      int b = m / 784, n = m - b * 784;   // n is a multiple of 8
      uint4 v = *(uint4*)&smem[cl * VSTR + mc * 8];
      *(uint4*)&vto[(((size_t)b * NH + h) * VD + cbase + cl) * Nseq + n] = v;
    }
  }
}

// ---------------- K2: flash attention, 32x32 MFMA, register-resident P ----------------
// UNCHANGED (parked at its co-saturation plateau; R7 confirmed R6's slowdown was env noise).
__global__ __launch_bounds__(256, 2) void attn_kernel(
    const unsigned short* __restrict__ qb,   // [bh][784][64] (pre-scaled by 0.125*log2e)
    const unsigned short* __restrict__ kb,   // [bh][784][64]
    const unsigned short* __restrict__ vtb,  // [bh][256][784], n-permuted
    const unsigned short* __restrict__ bias_tab, // [8][784][784] bf16, col-permuted
    unsigned short* __restrict__ U)          // [16*784*2048] bf16 (post-SiLU)
{
  __shared__ unsigned short vt_lds[2 * 256 * 64];  // 64 KB, dbuf, swizzled
  __shared__ unsigned short k_lds[2 * 64 * 64];    // 16 KB, dbuf, swizzled
  int tid = threadIdx.x;
  int wave = tid >> 6, lane = tid & 63;
  int lo = lane & 31, hi = lane >> 5;

  int L = blockIdx.x;
  int xcd = L & 7;
  int s = L >> 3;            // 0..111
  int qp = s % 7;            // 128-row Q group
  int bg = s / 7;            // batch
  int bh = bg * 8 + xcd;     // bh % 8 == h == xcd (head-bias L2 locality)
  int b = bg, h = xcd;

  int qrow_g = qp * 128 + wave * 32 + lo;          // this lane's q row
  int qrow = qrow_g < Nseq ? qrow_g : Nseq - 1;    // clamp dead rows

  int lc = lane >> 3;              // 0..7 (row-sub for glds)
  int lch = (lane & 7) ^ lc;       // swizzled 16B chunk this lane fetches
  int swz = lo & 7;                // read-side swizzle key (== row&7 for all our reads)

  const unsigned short* vsrc = vtb + ((size_t)bh * VD + wave * 64 + lc) * Nseq + lch * 8;
  const unsigned short* ksrc = kb + ((size_t)bh * Nseq + wave * 16 + lc) * KD + lch * 8;
  const unsigned short* brow = bias_tab + (size_t)h * NN + (size_t)qrow * Nseq + 8 * hi;

  // Q fragments first (oldest vm ops)
  short8 qf[4];
  {
    const unsigned short* qp_ = qb + ((size_t)bh * Nseq + qrow) * KD + hi * 8;
#pragma unroll
    for (int kst = 0; kst < 4; ++kst) qf[kst] = *(const short8*)(qp_ + kst * 16);
  }

  // ---- prologue: issue tile 0 (10 glds) + bias tile 0 (4 tracked dwordx4) ----
#pragma unroll
  for (int i = 0; i < 8; ++i) glds16(vsrc + i * (8 * Nseq), &vt_lds[wave * 4096 + i * 512]);
  glds16(ksrc, &k_lds[wave * 1024]);
  glds16(ksrc + 8 * KD, &k_lds[wave * 1024 + 512]);
  u32x4 bbC[4], bbN[4];
#pragma unroll
  for (int g = 0; g < 4; ++g) bbC[g] = *(const u32x4*)(brow + g * 16);

  f32x16 oacc[8];
#pragma unroll
  for (int ct = 0; ct < 8; ++ct) oacc[ct] = (f32x16)0.0f;
  float lsum = 0.0f;

  for (int kt = 0; kt < 13; ++kt) {
    int cur = kt & 1, nb = cur ^ 1;
    __builtin_amdgcn_s_waitcnt(0xC07F);   // lgkmcnt(0) only
    __builtin_amdgcn_s_barrier();
    int ktn = kt + 1; if (ktn >= 13) ktn = 0;   // wrap keeps vmcnt uniform
#pragma unroll
    for (int i = 0; i < 8; ++i)
      glds16(vsrc + i * (8 * Nseq) + ktn * 64, &vt_lds[nb * 16384 + wave * 4096 + i * 512]);
    glds16(ksrc + ktn * (64 * KD), &k_lds[nb * 4096 + wave * 1024]);
    glds16(ksrc + ktn * (64 * KD) + 8 * KD, &k_lds[nb * 4096 + wave * 1024 + 512]);
    // bias for NEXT tile (tracked loads; compiler inserts its own precise wait at use)
#pragma unroll
    for (int g = 0; g < 4; ++g) bbN[g] = *(const u32x4*)(brow + ktn * 64 + g * 16);

    // S^T accumulators initialized with bias — pure reg ops on LAST tile's loads,
    // hoisted before the vmcnt+barrier so the unpack runs under the barrier wait.
    f32x16 st0, st1;
#pragma unroll
    for (int r = 0; r < 16; ++r) {
      unsigned c0 = bbC[r >> 3][(r >> 1) & 3];
      unsigned c1 = bbC[2 + (r >> 3)][(r >> 1) & 3];
      st0[r] = (r & 1) ? bfHI(c0) : bfLO(c0);
      st1[r] = (r & 1) ? bfHI(c1) : bfLO(c1);
    }

    __builtin_amdgcn_s_waitcnt(0x0F7E);   // vmcnt(14): tile kt + bias kt landed; kt+1 in flight
    __builtin_amdgcn_s_barrier();

    const unsigned short* kbuf = &k_lds[cur * 4096];
    const unsigned short* vbuf = &vt_lds[cur * 16384];

    __builtin_amdgcn_s_setprio(1);
#pragma unroll
    for (int kst = 0; kst < 4; ++kst) {
      int ch = ((kst * 2 + hi) ^ swz) * 8;
      short8 kf0 = *(const short8*)&kbuf[lo * 64 + ch];
      short8 kf1 = *(const short8*)&kbuf[(32 + lo) * 64 + ch];
      st0 = __builtin_amdgcn_mfma_f32_32x32x16_bf16(kf0, qf[kst], st0, 0, 0, 0);
      st1 = __builtin_amdgcn_mfma_f32_32x32x16_bf16(kf1, qf[kst], st1, 0, 0, 0);
    }
    __builtin_amdgcn_s_setprio(0);

    // Interleaved softmax + PV per kst-group: exp2(8) -> partial sum -> pack -> 8 MFMAs.
    bool tail = (kt == 12);
    float lp0 = 0.0f, lp1 = 0.0f, lp2 = 0.0f, lp3 = 0.0f;
#pragma unroll
    for (int kst = 0; kst < 4; ++kst) {
      float p0, p1, p2, p3, p4, p5, p6, p7;
      if (kst == 0)      { p0=st0[0]; p1=st0[1]; p2=st0[2];  p3=st0[3];  p4=st0[4];  p5=st0[5];  p6=st0[6];  p7=st0[7];  }
      else if (kst == 1) { p0=st0[8]; p1=st0[9]; p2=st0[10]; p3=st0[11]; p4=st0[12]; p5=st0[13]; p6=st0[14]; p7=st0[15]; }
      else if (kst == 2) { p0=st1[0]; p1=st1[1]; p2=st1[2];  p3=st1[3];  p4=st1[4];  p5=st1[5];  p6=st1[6];  p7=st1[7];  }
      else               { p0=st1[8]; p1=st1[9]; p2=st1[10]; p3=st1[11]; p4=st1[12]; p5=st1[13]; p6=st1[14]; p7=st1[15]; }
      p0 = EXP2(p0); p1 = EXP2(p1); p2 = EXP2(p2); p3 = EXP2(p3);
      p4 = EXP2(p4); p5 = EXP2(p5); p6 = EXP2(p6); p7 = EXP2(p7);
      if (tail && kst > 0) { p0=0; p1=0; p2=0; p3=0; p4=0; p5=0; p6=0; p7=0; }
      float ls = ((p0 + p1) + (p2 + p3)) + ((p4 + p5) + (p6 + p7));
      if (kst == 0) lp0 = ls; else if (kst == 1) lp1 = ls; else if (kst == 2) lp2 = ls; else lp3 = ls;
      unsigned X0, X1, Y0, Y1;
      asm("v_cvt_pk_bf16_f32 %0, %1, %2" : "=v"(X0) : "v"(p0), "v"(p1));
      asm("v_cvt_pk_bf16_f32 %0, %1, %2" : "=v"(X1) : "v"(p2), "v"(p3));
      asm("v_cvt_pk_bf16_f32 %0, %1, %2" : "=v"(Y0) : "v"(p4), "v"(p5));
      asm("v_cvt_pk_bf16_f32 %0, %1, %2" : "=v"(Y1) : "v"(p6), "v"(p7));
      union { unsigned u[4]; short8 s; } pk_;
      pk_.u[0] = X0; pk_.u[1] = X1; pk_.u[2] = Y0; pk_.u[3] = Y1;
      short8 pf = pk_.s;

      int ch = ((kst * 2 + hi) ^ swz) * 8;
      const unsigned short* vr0 = &vbuf[lo * 64 + ch];
      __builtin_amdgcn_s_setprio(1);
#pragma unroll
      for (int ct = 0; ct < 8; ++ct) {
        short8 vf = *(const short8*)&vr0[ct * 2048];
        oacc[ct] = __builtin_amdgcn_mfma_f32_32x32x16_bf16(vf, pf, oacc[ct], 0, 0, 0);
      }
      __builtin_amdgcn_s_setprio(0);
    }
    lsum += (lp0 + lp1) + (lp2 + lp3);

#pragma unroll
    for (int g = 0; g < 4; ++g) bbC[g] = bbN[g];
  }

  __builtin_amdgcn_s_waitcnt(0x0070);   // drain wrapped prefetch before LDS goes out of scope

  // epilogue: row sum across the two kv-halves, SiLU, write
  float tot = lsum + __shfl_xor(lsum, 32);
  float inv = 1.0f / tot;
  if (qrow_g < Nseq) {
    size_t base = ((size_t)b * Nseq + qrow_g) * HV + h * VD;
#pragma unroll
    for (int ct = 0; ct < 8; ++ct)
#pragma unroll
      for (int g2 = 0; g2 < 4; ++g2) {
        ushort4 o4;
#pragma unroll
        for (int r4 = 0; r4 < 4; ++r4) {
          float u = oacc[ct][g2 * 4 + r4] * inv;
          float sg = 1.0f / (1.0f + EXP2(-u * 1.44269504f));
          ((unsigned short*)&o4)[r4] = f2bf(u * sg);
        }
        *(ushort4*)&U[base + ct * 32 + g2 * 8 + hi * 4] = o4;
      }
  }
}

// ---------------- K3: proj GEMM (dbuf glds pipeline, operand-swapped) + BN ----------------
// UNCHANGED from R7.
__global__ __launch_bounds__(256, 4) void proj_gemm_kernel(
    const unsigned short* __restrict__ Ubuf,  // [12544][2048]
    const unsigned short* __restrict__ Wp,    // [512][2048]
    const float* __restrict__ gamma, const float* __restrict__ beta,
    const float* __restrict__ mean,  const float* __restrict__ var,
    float* __restrict__ out)                  // [12544][512]
{
  const int K = HV;
  __shared__ unsigned short smem[16384];   // As[2][4096] + Bs[2][4096]
  int tid = threadIdx.x;
  int wave = tid >> 6, lane = tid & 63;
  int quad = lane >> 4, l16 = lane & 15;
  int wm = wave >> 1, wn = wave & 1;
  // XCD-chunked bijective swizzle: 392 = 8 * 49
  int bid = blockIdx.x;
  int wgid = (bid & 7) * 49 + (bid >> 3);
  int mB = (wgid % 98) * 128, o0 = (wgid / 98) * 128;

  int srow = wave * 32 + (lane >> 2);
  int sch = (lane & 3) * 8;
  const unsigned short* Ab = Wp + (size_t)(o0 + srow) * K + sch;
  const unsigned short* Bb = Ubuf + (size_t)(mB + srow) * K + sch;
  unsigned short* AsW = &smem[wave * 1024];
  unsigned short* BsW = &smem[4096 + wave * 1024];

  floatx4 acc[4][4];
  for (int i = 0; i < 4; ++i)
    for (int j = 0; j < 4; ++j) acc[i][j] = (floatx4)0.0f;

  glds16(Ab, AsW);
  glds16(Ab + 16 * K, AsW + 512);
  glds16(Bb, BsW);
  glds16(Bb + 16 * K, BsW + 512);

  for (int k = 0; k < 64; ++k) {
    int cur = k & 1, nb = cur ^ 1;
    __builtin_amdgcn_s_waitcnt(0xC07F);
    __builtin_amdgcn_s_barrier();
    int k0n = ((k + 1) & 63) * 32;
    glds16(Ab + k0n, AsW + nb * 8192);
    glds16(Ab + k0n + 16 * K, AsW + nb * 8192 + 512);
    glds16(Bb + k0n, BsW + nb * 8192);
    glds16(Bb + k0n + 16 * K, BsW + nb * 8192 + 512);
    __builtin_amdgcn_s_waitcnt(0x0F74);   // vmcnt(4)
    __builtin_amdgcn_s_barrier();

    const unsigned short* As = &smem[cur * 8192];
    const unsigned short* Bs = &smem[4096 + cur * 8192];
    short8 af[4], bfr[4];
    for (int mt = 0; mt < 4; ++mt)
      af[mt] = *(const short8*)&As[(wm * 64 + mt * 16 + l16) * 32 + quad * 8];
    for (int nt = 0; nt < 4; ++nt)
      bfr[nt] = *(const short8*)&Bs[(wn * 64 + nt * 16 + l16) * 32 + quad * 8];
    for (int mt = 0; mt < 4; ++mt)
      for (int nt = 0; nt < 4; ++nt)
        acc[mt][nt] = __builtin_amdgcn_mfma_f32_16x16x32_bf16(af[mt], bfr[nt], acc[mt][nt], 0, 0, 0);
  }
  __builtin_amdgcn_s_waitcnt(0x0070);   // drain wrapped prefetch

  for (int mt = 0; mt < 4; ++mt) {
    int ob = o0 + wm * 64 + mt * 16 + quad * 4;
    float4 g = *(const float4*)&gamma[ob];
    float4 vr = *(const float4*)&var[ob];
    float4 mn = *(const float4*)&mean[ob];
    float4 bt = *(const float4*)&beta[ob];
    float sc0 = g.x * rsqrtf(vr.x + 1e-5f), bb0 = bt.x - mn.x * sc0;
    float sc1 = g.y * rsqrtf(vr.y + 1e-5f), bb1 = bt.y - mn.y * sc1;
    float sc2 = g.z * rsqrtf(vr.z + 1e-5f), bb2 = bt.z - mn.z * sc2;
    float sc3 = g.w * rsqrtf(vr.w + 1e-5f), bb3 = bt.w - mn.w * sc3;
    for (int nt = 0; nt < 4; ++nt) {
      int m = mB + wn * 64 + nt * 16 + l16;
      float4 v;
      v.x = acc[mt][nt][0] * sc0 + bb0;
      v.y = acc[mt][nt][1] * sc1 + bb1;
      v.z = acc[mt][nt][2] * sc2 + bb2;
      v.w = acc[mt][nt][3] * sc3 + bb3;
      *(float4*)&out[(size_t)m * DIM + ob] = v;
    }
  }
}

// ---------------- launch ----------------
extern "C" void kernel_launch(void* const* d_in, const int* in_sizes, int n_in,
                              void* d_out, int out_size, void* d_ws, size_t ws_size,
                              hipStream_t stream) {
  const float* x          = (const float*)d_in[0];
  const float* qkv_w      = (const float*)d_in[1];
  const float* qkv_gamma  = (const float*)d_in[2];
  const float* qkv_beta   = (const float*)d_in[3];
  const float* qkv_mean   = (const float*)d_in[4];
  const float* qkv_var    = (const float*)d_in[5];
  const float* att_biases = (const float*)d_in[6];
  const float* proj_w     = (const float*)d_in[7];
  const float* proj_gamma = (const float*)d_in[8];
  const float* proj_beta  = (const float*)d_in[9];
  const float* proj_mean  = (const float*)d_in[10];
  const float* proj_var   = (const float*)d_in[11];
  const int*   bias_idxs  = (const int*)d_in[12];
  float* out = (float*)d_out;

  char* ws = (char*)d_ws;
  unsigned short* xb  = (unsigned short*)(ws);                 // 12544*512 (12.85 MB)
  unsigned short* bias_tab = (unsigned short*)(ws);            // 8*784*784 bf16 — aliases xb (dead after qkv_gemm)
  unsigned short* wq  = (unsigned short*)(ws + 12845056);      // 3072*512
  unsigned short* wp  = (unsigned short*)(ws + 15990784);      // 512*2048
  unsigned short* qo  = (unsigned short*)(ws + 18087936);      // 16*8*784*64
  unsigned short* ko  = (unsigned short*)(ws + 30932992);      // 16*8*784*64
  unsigned short* vto = (unsigned short*)(ws + 43778048);      // 16*8*256*784
  unsigned short* Ub  = (unsigned short*)(ws + 95158272);      // 12544*2048
  // total: 146538496 bytes

  {
    int n4 = N4X + N4Q + N4P;
    cvt_all_kernel<<<(n4 + 255) / 256, 256, 0, stream>>>(x, qkv_w, proj_w, xb, wq, wp);
  }

  qkv_gemm_kernel<<<1176, 256, 0, stream>>>(
      xb, wq, qkv_gamma, qkv_beta, qkv_mean, qkv_var, qo, ko, vto);

  bias_pre_kernel<<<(NN + 255) / 256, 256, 0, stream>>>(att_biases, bias_idxs, bias_tab);

  attn_kernel<<<7 * Bsz * NH, 256, 0, stream>>>(qo, ko, vto, bias_tab, Ub);

  proj_gemm_kernel<<<392, 256, 0, stream>>>(
      Ub, wp, proj_gamma, proj_beta, proj_mean, proj_var, out);
}

// Round 9
// 295.194 us; speedup vs baseline: 1.0278x; 1.0278x over previous
//
#include <hip/hip_runtime.h>

// Problem constants
#define Bsz 16
#define Nseq 784
#define DIM 512
#define NH 8
#define KD 64
#define VD 256
#define QKV_OUT 3072   // (2*64+256)*8
#define HV 2048        // NH*VD
#define NN 614656      // 784*784

typedef __attribute__((ext_vector_type(8))) short short8;
typedef __attribute__((ext_vector_type(4))) float floatx4;
typedef __attribute__((ext_vector_type(16))) float f32x16;
typedef __attribute__((ext_vector_type(4))) unsigned u32x4;

#define OSTR 136  // LDS row stride for qkv epilogue tile (bf16): 272B, 16B-aligned

#if __has_builtin(__builtin_amdgcn_exp2f)
#define EXP2(x) __builtin_amdgcn_exp2f(x)
#else
#define EXP2(x) exp2f(x)
#endif

__device__ __forceinline__ unsigned short f2bf(float f) {
  union { float f; unsigned u; } v; v.f = f;
  unsigned r = v.u + 0x7fffu + ((v.u >> 16) & 1u);
  return (unsigned short)(r >> 16);
}
__device__ __forceinline__ float bfLO(unsigned u) {
  union { unsigned u; float f; } v; v.u = u << 16; return v.f;
}
__device__ __forceinline__ float bfHI(unsigned u) {
  union { unsigned u; float f; } v; v.u = u & 0xffff0000u; return v.f;
}

// async global->LDS, 16B per lane; LDS dst = wave-uniform base + lane*16
__device__ __forceinline__ void glds16(const unsigned short* g, unsigned short* l) {
  __builtin_amdgcn_global_load_lds(
      (const __attribute__((address_space(1))) void*)g,
      (__attribute__((address_space(3))) void*)l, 16, 0, 0);
}

// ---------------- K0: fused fp32 -> bf16 convert (x, qkv_w, proj_w) ----------------
#define N4X 1605632   // x float4s
#define N4Q 393216    // qkv_w float4s
#define N4P 262144    // proj_w float4s
__global__ void cvt_all_kernel(const float* __restrict__ x,
                               const float* __restrict__ qw,
                               const float* __restrict__ pw,
                               unsigned short* __restrict__ xb,
                               unsigned short* __restrict__ wq,
                               unsigned short* __restrict__ wp) {
  int i = blockIdx.x * 256 + threadIdx.x;
  const float4* s; ushort4* d; int off;
  if (i < N4X)              { s = (const float4*)x;  d = (ushort4*)xb; off = i; }
  else if (i < N4X + N4Q)   { s = (const float4*)qw; d = (ushort4*)wq; off = i - N4X; }
  else if (i < N4X + N4Q + N4P) { s = (const float4*)pw; d = (ushort4*)wp; off = i - N4X - N4Q; }
  else return;
  float4 v = s[off];
  ushort4 o;
  o.x = f2bf(v.x); o.y = f2bf(v.y); o.z = f2bf(v.z); o.w = f2bf(v.w);
  d[off] = o;
}

// ---------------- K0b: bias table [8][784][784] bf16, log2e-folded, columns bit2<->bit3 permuted ----------------
__global__ void bias_pre_kernel(const float* __restrict__ biases,
                                const int* __restrict__ bias_idxs,
                                unsigned short* __restrict__ bias_tab) {
  int t = blockIdx.x * 256 + threadIdx.x;
  if (t >= NN) return;
  int idx = bias_idxs[t];
  // 784 % 16 == 0, so swapping bits 2,3 of the flat index permutes within the column part
  int p = (t & ~12) | ((t & 4) << 1) | ((t & 8) >> 1);
  for (int h = 0; h < NH; ++h)
    bias_tab[(size_t)h * NN + p] = f2bf(1.44269504f * biases[h * Nseq + idx]);
}

// ---------------- K1: QKV GEMM, 128^2 tile, TRIPLE-buffered glds, prefetch depth 2 ----------------
// R8 post-mortem: 2-phase + depth-1 prefetch is latency-bound at K=512 (vmcnt wait exposes
// HBM/L2 latency every k-step; occupancy/L2/tile-size all proven non-binding R5-R8).
// Fix = T4 counted vmcnt with depth 2: stage k+2, wait vmcnt(8) -> each load gets 2 full
// k-steps to land. Staging 3 x 16KB = 48KB; epilogue arena (34.8KB) aliases it.
__global__ __launch_bounds__(256, 3) void qkv_gemm_kernel(
    const unsigned short* __restrict__ A,
    const unsigned short* __restrict__ Bw,
    const float* __restrict__ gamma, const float* __restrict__ beta,
    const float* __restrict__ mean,  const float* __restrict__ var,
    unsigned short* __restrict__ qo,   // [B,H,N,64] (pre-scaled by 0.125*log2e)
    unsigned short* __restrict__ ko,   // [B,H,N,64]
    unsigned short* __restrict__ vto)  // [B,H,256,N] with n-dim bit2<->bit3 permuted
{
  const int K = DIM;
  __shared__ unsigned short smem[24576];  // 49152B: 3 x [A 4096 | B 4096] shorts
  int tid = threadIdx.x;
  int wave = tid >> 6, lane = tid & 63;
  int quad = lane >> 4, l16 = lane & 15;
  int wm = wave >> 1, wn = wave & 1;
  // XCD-chunked bijective swizzle: 2352 = 8 * 294
  int bid = blockIdx.x;
  int wgid = (bid & 7) * 294 + (bid >> 3);
  int m0 = (wgid / 24) * 128, n0 = (wgid % 24) * 128;

  int srow = wave * 32 + (lane >> 2);
  int sch = (lane & 3) * 8;
  const unsigned short* Ab = A + (size_t)(m0 + srow) * K + sch;
  const unsigned short* Bb = Bw + (size_t)(n0 + srow) * K + sch;

  floatx4 acc[4][4];
  for (int i = 0; i < 4; ++i)
    for (int j = 0; j < 4; ++j) acc[i][j] = (floatx4)0.0f;

#define STAGE_QKV(kk, buf) do {                                          \
    int off_ = ((kk) & 15) * 32;                                         \
    unsigned short* As_ = &smem[(buf) * 8192 + wave * 1024];             \
    unsigned short* Bs_ = &smem[(buf) * 8192 + 4096 + wave * 1024];      \
    glds16(Ab + off_, As_); glds16(Ab + off_ + 16 * K, As_ + 512);       \
    glds16(Bb + off_, Bs_); glds16(Bb + off_ + 16 * K, Bs_ + 512);       \
  } while (0)

  // prologue: stage k=0 -> buf0, k=1 -> buf1
  STAGE_QKV(0, 0);
  STAGE_QKV(1, 1);

  for (int k = 0; k < 16; ++k) {
    int cur = k % 3;
    int nxt = (k + 2) % 3;
    __builtin_amdgcn_s_waitcnt(0xC07F);   // lgkmcnt(0): own reads of buf nxt (step k-1) done
    __builtin_amdgcn_s_barrier();         // all waves done with buf nxt
    STAGE_QKV(k + 2, nxt);                // wrap keeps vmcnt uniform
    __builtin_amdgcn_s_waitcnt(0x0F78);   // vmcnt(8): step k landed; k+1,k+2 in flight
    __builtin_amdgcn_s_barrier();

    const unsigned short* As = &smem[cur * 8192];
    const unsigned short* Bs = &smem[cur * 8192 + 4096];
    short8 af[4], bfr[4];
    for (int mt = 0; mt < 4; ++mt)
      af[mt] = *(const short8*)&As[(wm * 64 + mt * 16 + l16) * 32 + quad * 8];
    for (int nt = 0; nt < 4; ++nt)
      bfr[nt] = *(const short8*)&Bs[(wn * 64 + nt * 16 + l16) * 32 + quad * 8];
    for (int mt = 0; mt < 4; ++mt)
      for (int nt = 0; nt < 4; ++nt)
        acc[mt][nt] = __builtin_amdgcn_mfma_f32_16x16x32_bf16(af[mt], bfr[nt], acc[mt][nt], 0, 0, 0);
  }
#undef STAGE_QKV

  int tt = n0 % 384;        // 0 => QK tile; 128/256 => V tile
  int h = n0 / 384;
  __builtin_amdgcn_s_waitcnt(0x0070);   // drain wrapped prefetch before smem reuse
  __syncthreads();

  if (tt == 0) {
    for (int nt = 0; nt < 4; ++nt) {
      int o = n0 + wn * 64 + nt * 16 + l16;
      float sc = gamma[o] * rsqrtf(var[o] + 1e-5f);
      float bb = beta[o] - mean[o] * sc;
      if (wn == 0) { sc *= 0.18033688f; bb *= 0.18033688f; }  // 0.125 * log2e folded into Q
      int jl = wn * 64 + nt * 16 + l16;
      for (int mt = 0; mt < 4; ++mt)
        for (int r = 0; r < 4; ++r) {
          int ml = wm * 64 + mt * 16 + quad * 4 + r;
          smem[ml * OSTR + jl] = f2bf(acc[mt][nt][r] * sc + bb);
        }
    }
    __syncthreads();
    for (int i = 0; i < 8; ++i) {
      int c = i * 256 + tid;
      int ml = c >> 4, jc = c & 15;
      int m = m0 + ml;
      int b = m / 784, n = m - b * 784;
      uint4 v = *(uint4*)&smem[ml * OSTR + jc * 8];
      int j = jc * 8;
      if (j < 64) *(uint4*)&qo[(((size_t)b * NH + h) * Nseq + n) * KD + j] = v;
      else        *(uint4*)&ko[(((size_t)b * NH + h) * Nseq + n) * KD + (j - 64)] = v;
    }
  } else {
    for (int nt = 0; nt < 4; ++nt) {
      int o = n0 + wn * 64 + nt * 16 + l16;
      float sc = gamma[o] * rsqrtf(var[o] + 1e-5f);
      float bb = beta[o] - mean[o] * sc;
      int cl = wn * 64 + nt * 16 + l16;
      // kv bit2<->bit3 permutation folded into the LDS write index (quad bit swap)
      int qperm = (quad & 1) * 8 + (quad >> 1) * 4;
      for (int mt = 0; mt < 4; ++mt) {
        int ml0 = wm * 64 + mt * 16 + qperm;
        ushort4 pk;
        pk.x = f2bf(acc[mt][nt][0] * sc + bb);
        pk.y = f2bf(acc[mt][nt][1] * sc + bb);
        pk.z = f2bf(acc[mt][nt][2] * sc + bb);
        pk.w = f2bf(acc[mt][nt][3] * sc + bb);
        *(ushort4*)&smem[cl * OSTR + ml0] = pk;
      }
    }
    __syncthreads();
    int cbase = tt - 128;
    for (int i = 0; i < 8; ++i) {
      int c = i * 256 + tid;
      int cl = c >> 4, mc = c & 15;
      int m = m0 + mc * 8;
      int b = m / 784, n = m - b * 784;   // n is a multiple of 8
      uint4 v = *(uint4*)&smem[cl * OSTR + mc * 8];
      *(uint4*)&vto[(((size_t)b * NH + h) * VD + cbase + cl) * Nseq + n] = v;
    }
  }
}

// ---------------- K2: flash attention, 32x32 MFMA, register-resident P ----------------
// UNCHANGED (parked at its co-saturation plateau).
__global__ __launch_bounds__(256, 2) void attn_kernel(
    const unsigned short* __restrict__ qb,   // [bh][784][64] (pre-scaled by 0.125*log2e)
    const unsigned short* __restrict__ kb,   // [bh][784][64]
    const unsigned short* __restrict__ vtb,  // [bh][256][784], n-permuted
    const unsigned short* __restrict__ bias_tab, // [8][784][784] bf16, col-permuted
    unsigned short* __restrict__ U)          // [16*784*2048] bf16 (post-SiLU)
{
  __shared__ unsigned short vt_lds[2 * 256 * 64];  // 64 KB, dbuf, swizzled
  __shared__ unsigned short k_lds[2 * 64 * 64];    // 16 KB, dbuf, swizzled
  int tid = threadIdx.x;
  int wave = tid >> 6, lane = tid & 63;
  int lo = lane & 31, hi = lane >> 5;

  int L = blockIdx.x;
  int xcd = L & 7;
  int s = L >> 3;            // 0..111
  int qp = s % 7;            // 128-row Q group
  int bg = s / 7;            // batch
  int bh = bg * 8 + xcd;     // bh % 8 == h == xcd (head-bias L2 locality)
  int b = bg, h = xcd;

  int qrow_g = qp * 128 + wave * 32 + lo;          // this lane's q row
  int qrow = qrow_g < Nseq ? qrow_g : Nseq - 1;    // clamp dead rows

  int lc = lane >> 3;              // 0..7 (row-sub for glds)
  int lch = (lane & 7) ^ lc;       // swizzled 16B chunk this lane fetches
  int swz = lo & 7;                // read-side swizzle key (== row&7 for all our reads)

  const unsigned short* vsrc = vtb + ((size_t)bh * VD + wave * 64 + lc) * Nseq + lch * 8;
  const unsigned short* ksrc = kb + ((size_t)bh * Nseq + wave * 16 + lc) * KD + lch * 8;
  const unsigned short* brow = bias_tab + (size_t)h * NN + (size_t)qrow * Nseq + 8 * hi;

  // Q fragments first (oldest vm ops)
  short8 qf[4];
  {
    const unsigned short* qp_ = qb + ((size_t)bh * Nseq + qrow) * KD + hi * 8;
#pragma unroll
    for (int kst = 0; kst < 4; ++kst) qf[kst] = *(const short8*)(qp_ + kst * 16);
  }

  // ---- prologue: issue tile 0 (10 glds) + bias tile 0 (4 tracked dwordx4) ----
#pragma unroll
  for (int i = 0; i < 8; ++i) glds16(vsrc + i * (8 * Nseq), &vt_lds[wave * 4096 + i * 512]);
  glds16(ksrc, &k_lds[wave * 1024]);
  glds16(ksrc + 8 * KD, &k_lds[wave * 1024 + 512]);
  u32x4 bbC[4], bbN[4];
#pragma unroll
  for (int g = 0; g < 4; ++g) bbC[g] = *(const u32x4*)(brow + g * 16);

  f32x16 oacc[8];
#pragma unroll
  for (int ct = 0; ct < 8; ++ct) oacc[ct] = (f32x16)0.0f;
  float lsum = 0.0f;

  for (int kt = 0; kt < 13; ++kt) {
    int cur = kt & 1, nb = cur ^ 1;
    __builtin_amdgcn_s_waitcnt(0xC07F);   // lgkmcnt(0) only
    __builtin_amdgcn_s_barrier();
    int ktn = kt + 1; if (ktn >= 13) ktn = 0;   // wrap keeps vmcnt uniform
#pragma unroll
    for (int i = 0; i < 8; ++i)
      glds16(vsrc + i * (8 * Nseq) + ktn * 64, &vt_lds[nb * 16384 + wave * 4096 + i * 512]);
    glds16(ksrc + ktn * (64 * KD), &k_lds[nb * 4096 + wave * 1024]);
    glds16(ksrc + ktn * (64 * KD) + 8 * KD, &k_lds[nb * 4096 + wave * 1024 + 512]);
    // bias for NEXT tile (tracked loads; compiler inserts its own precise wait at use)
#pragma unroll
    for (int g = 0; g < 4; ++g) bbN[g] = *(const u32x4*)(brow + ktn * 64 + g * 16);

    // S^T accumulators initialized with bias — pure reg ops on LAST tile's loads,
    // hoisted before the vmcnt+barrier so the unpack runs under the barrier wait.
    f32x16 st0, st1;
#pragma unroll
    for (int r = 0; r < 16; ++r) {
      unsigned c0 = bbC[r >> 3][(r >> 1) & 3];
      unsigned c1 = bbC[2 + (r >> 3)][(r >> 1) & 3];
      st0[r] = (r & 1) ? bfHI(c0) : bfLO(c0);
      st1[r] = (r & 1) ? bfHI(c1) : bfLO(c1);
    }

    __builtin_amdgcn_s_waitcnt(0x0F7E);   // vmcnt(14): tile kt + bias kt landed; kt+1 in flight
    __builtin_amdgcn_s_barrier();

    const unsigned short* kbuf = &k_lds[cur * 4096];
    const unsigned short* vbuf = &vt_lds[cur * 16384];

    __builtin_amdgcn_s_setprio(1);
#pragma unroll
    for (int kst = 0; kst < 4; ++kst) {
      int ch = ((kst * 2 + hi) ^ swz) * 8;
      short8 kf0 = *(const short8*)&kbuf[lo * 64 + ch];
      short8 kf1 = *(const short8*)&kbuf[(32 + lo) * 64 + ch];
      st0 = __builtin_amdgcn_mfma_f32_32x32x16_bf16(kf0, qf[kst], st0, 0, 0, 0);
      st1 = __builtin_amdgcn_mfma_f32_32x32x16_bf16(kf1, qf[kst], st1, 0, 0, 0);
    }
    __builtin_amdgcn_s_setprio(0);

    // Interleaved softmax + PV per kst-group: exp2(8) -> partial sum -> pack -> 8 MFMAs.
    bool tail = (kt == 12);
    float lp0 = 0.0f, lp1 = 0.0f, lp2 = 0.0f, lp3 = 0.0f;
#pragma unroll
    for (int kst = 0; kst < 4; ++kst) {
      float p0, p1, p2, p3, p4, p5, p6, p7;
      if (kst == 0)      { p0=st0[0]; p1=st0[1]; p2=st0[2];  p3=st0[3];  p4=st0[4];  p5=st0[5];  p6=st0[6];  p7=st0[7];  }
      else if (kst == 1) { p0=st0[8]; p1=st0[9]; p2=st0[10]; p3=st0[11]; p4=st0[12]; p5=st0[13]; p6=st0[14]; p7=st0[15]; }
      else if (kst == 2) { p0=st1[0]; p1=st1[1]; p2=st1[2];  p3=st1[3];  p4=st1[4];  p5=st1[5];  p6=st1[6];  p7=st1[7];  }
      else               { p0=st1[8]; p1=st1[9]; p2=st1[10]; p3=st1[11]; p4=st1[12]; p5=st1[13]; p6=st1[14]; p7=st1[15]; }
      p0 = EXP2(p0); p1 = EXP2(p1); p2 = EXP2(p2); p3 = EXP2(p3);
      p4 = EXP2(p4); p5 = EXP2(p5); p6 = EXP2(p6); p7 = EXP2(p7);
      if (tail && kst > 0) { p0=0; p1=0; p2=0; p3=0; p4=0; p5=0; p6=0; p7=0; }
      float ls = ((p0 + p1) + (p2 + p3)) + ((p4 + p5) + (p6 + p7));
      if (kst == 0) lp0 = ls; else if (kst == 1) lp1 = ls; else if (kst == 2) lp2 = ls; else lp3 = ls;
      unsigned X0, X1, Y0, Y1;
      asm("v_cvt_pk_bf16_f32 %0, %1, %2" : "=v"(X0) : "v"(p0), "v"(p1));
      asm("v_cvt_pk_bf16_f32 %0, %1, %2" : "=v"(X1) : "v"(p2), "v"(p3));
      asm("v_cvt_pk_bf16_f32 %0, %1, %2" : "=v"(Y0) : "v"(p4), "v"(p5));
      asm("v_cvt_pk_bf16_f32 %0, %1, %2" : "=v"(Y1) : "v"(p6), "v"(p7));
      union { unsigned u[4]; short8 s; } pk_;
      pk_.u[0] = X0; pk_.u[1] = X1; pk_.u[2] = Y0; pk_.u[3] = Y1;
      short8 pf = pk_.s;

      int ch = ((kst * 2 + hi) ^ swz) * 8;
      const unsigned short* vr0 = &vbuf[lo * 64 + ch];
      __builtin_amdgcn_s_setprio(1);
#pragma unroll
      for (int ct = 0; ct < 8; ++ct) {
        short8 vf = *(const short8*)&vr0[ct * 2048];
        oacc[ct] = __builtin_amdgcn_mfma_f32_32x32x16_bf16(vf, pf, oacc[ct], 0, 0, 0);
      }
      __builtin_amdgcn_s_setprio(0);
    }
    lsum += (lp0 + lp1) + (lp2 + lp3);

#pragma unroll
    for (int g = 0; g < 4; ++g) bbC[g] = bbN[g];
  }

  __builtin_amdgcn_s_waitcnt(0x0070);   // drain wrapped prefetch before LDS goes out of scope

  // epilogue: row sum across the two kv-halves, SiLU, write
  float tot = lsum + __shfl_xor(lsum, 32);
  float inv = 1.0f / tot;
  if (qrow_g < Nseq) {
    size_t base = ((size_t)b * Nseq + qrow_g) * HV + h * VD;
#pragma unroll
    for (int ct = 0; ct < 8; ++ct)
#pragma unroll
      for (int g2 = 0; g2 < 4; ++g2) {
        ushort4 o4;
#pragma unroll
        for (int r4 = 0; r4 < 4; ++r4) {
          float u = oacc[ct][g2 * 4 + r4] * inv;
          float sg = 1.0f / (1.0f + EXP2(-u * 1.44269504f));
          ((unsigned short*)&o4)[r4] = f2bf(u * sg);
        }
        *(ushort4*)&U[base + ct * 32 + g2 * 8 + hi * 4] = o4;
      }
  }
}

// ---------------- K3: proj GEMM, 128^2 tile, TRIPLE-buffered glds, prefetch depth 2 ----------------
__global__ __launch_bounds__(256, 3) void proj_gemm_kernel(
    const unsigned short* __restrict__ Ubuf,  // [12544][2048]
    const unsigned short* __restrict__ Wp,    // [512][2048]
    const float* __restrict__ gamma, const float* __restrict__ beta,
    const float* __restrict__ mean,  const float* __restrict__ var,
    float* __restrict__ out)                  // [12544][512]
{
  const int K = HV;
  __shared__ unsigned short smem[24576];   // 49152B: 3 x [A 4096 | B 4096] shorts
  int tid = threadIdx.x;
  int wave = tid >> 6, lane = tid & 63;
  int quad = lane >> 4, l16 = lane & 15;
  int wm = wave >> 1, wn = wave & 1;
  // XCD-chunked bijective swizzle: 392 = 8 * 49
  int bid = blockIdx.x;
  int wgid = (bid & 7) * 49 + (bid >> 3);
  int mB = (wgid % 98) * 128, o0 = (wgid / 98) * 128;

  int srow = wave * 32 + (lane >> 2);
  int sch = (lane & 3) * 8;
  const unsigned short* Ab = Wp + (size_t)(o0 + srow) * K + sch;
  const unsigned short* Bb = Ubuf + (size_t)(mB + srow) * K + sch;

  floatx4 acc[4][4];
  for (int i = 0; i < 4; ++i)
    for (int j = 0; j < 4; ++j) acc[i][j] = (floatx4)0.0f;

#define STAGE_PROJ(kk, buf) do {                                         \
    int off_ = ((kk) & 63) * 32;                                         \
    unsigned short* As_ = &smem[(buf) * 8192 + wave * 1024];             \
    unsigned short* Bs_ = &smem[(buf) * 8192 + 4096 + wave * 1024];      \
    glds16(Ab + off_, As_); glds16(Ab + off_ + 16 * K, As_ + 512);       \
    glds16(Bb + off_, Bs_); glds16(Bb + off_ + 16 * K, Bs_ + 512);       \
  } while (0)

  STAGE_PROJ(0, 0);
  STAGE_PROJ(1, 1);

  for (int k = 0; k < 64; ++k) {
    int cur = k % 3;
    int nxt = (k + 2) % 3;
    __builtin_amdgcn_s_waitcnt(0xC07F);
    __builtin_amdgcn_s_barrier();
    STAGE_PROJ(k + 2, nxt);
    __builtin_amdgcn_s_waitcnt(0x0F78);   // vmcnt(8)
    __builtin_amdgcn_s_barrier();

    const unsigned short* As = &smem[cur * 8192];
    const unsigned short* Bs = &smem[cur * 8192 + 4096];
    short8 af[4], bfr[4];
    for (int mt = 0; mt < 4; ++mt)
      af[mt] = *(const short8*)&As[(wm * 64 + mt * 16 + l16) * 32 + quad * 8];
    for (int nt = 0; nt < 4; ++nt)
      bfr[nt] = *(const short8*)&Bs[(wn * 64 + nt * 16 + l16) * 32 + quad * 8];
    for (int mt = 0; mt < 4; ++mt)
      for (int nt = 0; nt < 4; ++nt)
        acc[mt][nt] = __builtin_amdgcn_mfma_f32_16x16x32_bf16(af[mt], bfr[nt], acc[mt][nt], 0, 0, 0);
  }
#undef STAGE_PROJ
  __builtin_amdgcn_s_waitcnt(0x0070);   // drain wrapped prefetch

  for (int mt = 0; mt < 4; ++mt) {
    int ob = o0 + wm * 64 + mt * 16 + quad * 4;
    float4 g = *(const float4*)&gamma[ob];
    float4 vr = *(const float4*)&var[ob];
    float4 mn = *(const float4*)&mean[ob];
    float4 bt = *(const float4*)&beta[ob];
    float sc0 = g.x * rsqrtf(vr.x + 1e-5f), bb0 = bt.x - mn.x * sc0;
    float sc1 = g.y * rsqrtf(vr.y + 1e-5f), bb1 = bt.y - mn.y * sc1;
    float sc2 = g.z * rsqrtf(vr.z + 1e-5f), bb2 = bt.z - mn.z * sc2;
    float sc3 = g.w * rsqrtf(vr.w + 1e-5f), bb3 = bt.w - mn.w * sc3;
    for (int nt = 0; nt < 4; ++nt) {
      int m = mB + wn * 64 + nt * 16 + l16;
      float4 v;
      v.x = acc[mt][nt][0] * sc0 + bb0;
      v.y = acc[mt][nt][1] * sc1 + bb1;
      v.z = acc[mt][nt][2] * sc2 + bb2;
      v.w = acc[mt][nt][3] * sc3 + bb3;
      *(float4*)&out[(size_t)m * DIM + ob] = v;
    }
  }
}

// ---------------- launch ----------------
extern "C" void kernel_launch(void* const* d_in, const int* in_sizes, int n_in,
                              void* d_out, int out_size, void* d_ws, size_t ws_size,
                              hipStream_t stream) {
  const float* x          = (const float*)d_in[0];
  const float* qkv_w      = (const float*)d_in[1];
  const float* qkv_gamma  = (const float*)d_in[2];
  const float* qkv_beta   = (const float*)d_in[3];
  const float* qkv_mean   = (const float*)d_in[4];
  const float* qkv_var    = (const float*)d_in[5];
  const float* att_biases = (const float*)d_in[6];
  const float* proj_w     = (const float*)d_in[7];
  const float* proj_gamma = (const float*)d_in[8];
  const float* proj_beta  = (const float*)d_in[9];
  const float* proj_mean  = (const float*)d_in[10];
  const float* proj_var   = (const float*)d_in[11];
  const int*   bias_idxs  = (const int*)d_in[12];
  float* out = (float*)d_out;

  char* ws = (char*)d_ws;
  unsigned short* xb  = (unsigned short*)(ws);                 // 12544*512 (12.85 MB)
  unsigned short* bias_tab = (unsigned short*)(ws);            // 8*784*784 bf16 — aliases xb (dead after qkv_gemm)
  unsigned short* wq  = (unsigned short*)(ws + 12845056);      // 3072*512
  unsigned short* wp  = (unsigned short*)(ws + 15990784);      // 512*2048
  unsigned short* qo  = (unsigned short*)(ws + 18087936);      // 16*8*784*64
  unsigned short* ko  = (unsigned short*)(ws + 30932992);      // 16*8*784*64
  unsigned short* vto = (unsigned short*)(ws + 43778048);      // 16*8*256*784
  unsigned short* Ub  = (unsigned short*)(ws + 95158272);      // 12544*2048
  // total: 146538496 bytes

  {
    int n4 = N4X + N4Q + N4P;
    cvt_all_kernel<<<(n4 + 255) / 256, 256, 0, stream>>>(x, qkv_w, proj_w, xb, wq, wp);
  }

  qkv_gemm_kernel<<<2352, 256, 0, stream>>>(
      xb, wq, qkv_gamma, qkv_beta, qkv_mean, qkv_var, qo, ko, vto);

  bias_pre_kernel<<<(NN + 255) / 256, 256, 0, stream>>>(att_biases, bias_idxs, bias_tab);

  attn_kernel<<<7 * Bsz * NH, 256, 0, stream>>>(qo, ko, vto, bias_tab, Ub);

  proj_gemm_kernel<<<392, 256, 0, stream>>>(
      Ub, wp, proj_gamma, proj_beta, proj_mean, proj_var, out);
}

// Round 10
// 293.941 us; speedup vs baseline: 1.0321x; 1.0043x over previous
//
#include <hip/hip_runtime.h>

// Problem constants
#define Bsz 16
#define Nseq 784
#define DIM 512
#define NH 8
#define KD 64
#define VD 256
#define QKV_OUT 3072   // (2*64+256)*8
#define HV 2048        // NH*VD
#define NN 614656      // 784*784

typedef __attribute__((ext_vector_type(8))) short short8;
typedef __attribute__((ext_vector_type(4))) float floatx4;
typedef __attribute__((ext_vector_type(16))) float f32x16;
typedef __attribute__((ext_vector_type(4))) unsigned u32x4;

#define OSTR 136  // LDS row stride for qkv epilogue tile (bf16): 272B, 16B-aligned

#if __has_builtin(__builtin_amdgcn_exp2f)
#define EXP2(x) __builtin_amdgcn_exp2f(x)
#else
#define EXP2(x) exp2f(x)
#endif

__device__ __forceinline__ unsigned short f2bf(float f) {
  union { float f; unsigned u; } v; v.f = f;
  unsigned r = v.u + 0x7fffu + ((v.u >> 16) & 1u);
  return (unsigned short)(r >> 16);
}
__device__ __forceinline__ float bfLO(unsigned u) {
  union { unsigned u; float f; } v; v.u = u << 16; return v.f;
}
__device__ __forceinline__ float bfHI(unsigned u) {
  union { unsigned u; float f; } v; v.u = u & 0xffff0000u; return v.f;
}

// async global->LDS, 16B per lane; LDS dst = wave-uniform base + lane*16
__device__ __forceinline__ void glds16(const unsigned short* g, unsigned short* l) {
  __builtin_amdgcn_global_load_lds(
      (const __attribute__((address_space(1))) void*)g,
      (__attribute__((address_space(3))) void*)l, 16, 0, 0);
}

// ---------------- K0: fused fp32 -> bf16 convert (x, qkv_w, proj_w) ----------------
#define N4X 1605632   // x float4s
#define N4Q 393216    // qkv_w float4s
#define N4P 262144    // proj_w float4s
__global__ void cvt_all_kernel(const float* __restrict__ x,
                               const float* __restrict__ qw,
                               const float* __restrict__ pw,
                               unsigned short* __restrict__ xb,
                               unsigned short* __restrict__ wq,
                               unsigned short* __restrict__ wp) {
  int i = blockIdx.x * 256 + threadIdx.x;
  const float4* s; ushort4* d; int off;
  if (i < N4X)              { s = (const float4*)x;  d = (ushort4*)xb; off = i; }
  else if (i < N4X + N4Q)   { s = (const float4*)qw; d = (ushort4*)wq; off = i - N4X; }
  else if (i < N4X + N4Q + N4P) { s = (const float4*)pw; d = (ushort4*)wp; off = i - N4X - N4Q; }
  else return;
  float4 v = s[off];
  ushort4 o;
  o.x = f2bf(v.x); o.y = f2bf(v.y); o.z = f2bf(v.z); o.w = f2bf(v.w);
  d[off] = o;
}

// ---------------- K0b: bias table [8][784][784] bf16, log2e-folded, columns bit2<->bit3 permuted ----------------
__global__ void bias_pre_kernel(const float* __restrict__ biases,
                                const int* __restrict__ bias_idxs,
                                unsigned short* __restrict__ bias_tab) {
  int t = blockIdx.x * 256 + threadIdx.x;
  if (t >= NN) return;
  int idx = bias_idxs[t];
  // 784 % 16 == 0, so swapping bits 2,3 of the flat index permutes within the column part
  int p = (t & ~12) | ((t & 4) << 1) | ((t & 8) >> 1);
  for (int h = 0; h < NH; ++h)
    bias_tab[(size_t)h * NN + p] = f2bf(1.44269504f * biases[h * Nseq + idx]);
}

// ---------------- K1: QKV GEMM, 128^2 tile, BK=64 (2 sub-steps per sync pair) ----------------
// R9 post-mortem: depth-2 prefetch null -> stall is NOT load latency; it is the per-k-step
// sync pair itself (m233: stage+vmcnt+barrier ~70% of the 2-phase slot). Fix: halve the
// sync pairs. BK=64 stored as TWO independent [128][32] sub-tiles (identical layout and
// fragment reads as BK=32 — no new bank-conflict surface); one lgkm+barrier / vmcnt(8)+
// barrier pair now covers 32 MFMAs/wave. LDS: 2 bufs x (A0|B0|A1|B1) = 64KB; epilogue
// arena (34.8KB) aliases it.
__global__ __launch_bounds__(256, 2) void qkv_gemm_kernel(
    const unsigned short* __restrict__ A,
    const unsigned short* __restrict__ Bw,
    const float* __restrict__ gamma, const float* __restrict__ beta,
    const float* __restrict__ mean,  const float* __restrict__ var,
    unsigned short* __restrict__ qo,   // [B,H,N,64] (pre-scaled by 0.125*log2e)
    unsigned short* __restrict__ ko,   // [B,H,N,64]
    unsigned short* __restrict__ vto)  // [B,H,256,N] with n-dim bit2<->bit3 permuted
{
  const int K = DIM;
  __shared__ unsigned short smem[32768];  // 65536B: 2 bufs x [A0 4096|B0 4096|A1 4096|B1 4096]
  int tid = threadIdx.x;
  int wave = tid >> 6, lane = tid & 63;
  int quad = lane >> 4, l16 = lane & 15;
  int wm = wave >> 1, wn = wave & 1;
  // XCD-chunked bijective swizzle: 2352 = 8 * 294
  int bid = blockIdx.x;
  int wgid = (bid & 7) * 294 + (bid >> 3);
  int m0 = (wgid / 24) * 128, n0 = (wgid % 24) * 128;

  int srow = wave * 32 + (lane >> 2);
  int sch = (lane & 3) * 8;
  const unsigned short* Ab = A + (size_t)(m0 + srow) * K + sch;
  const unsigned short* Bb = Bw + (size_t)(n0 + srow) * K + sch;

  floatx4 acc[4][4];
  for (int i = 0; i < 4; ++i)
    for (int j = 0; j < 4; ++j) acc[i][j] = (floatx4)0.0f;

  // stage one 32-column sub-step kk32 into (buf, slot)
#define STAGE_QKV(kk32, buf, slot) do {                                        \
    int off_ = ((kk32) & 15) * 32;                                             \
    unsigned short* As_ = &smem[(buf) * 16384 + (slot) * 8192 + wave * 1024];  \
    unsigned short* Bs_ = As_ + 4096;                                          \
    glds16(Ab + off_, As_); glds16(Ab + off_ + 16 * K, As_ + 512);             \
    glds16(Bb + off_, Bs_); glds16(Bb + off_ + 16 * K, Bs_ + 512);             \
  } while (0)

  // prologue: big-tile 0 (sub-steps 0,1) into buf 0
  STAGE_QKV(0, 0, 0);
  STAGE_QKV(1, 0, 1);

  for (int t = 0; t < 8; ++t) {
    int cur = t & 1, nb = cur ^ 1;
    __builtin_amdgcn_s_waitcnt(0xC07F);   // lgkmcnt(0): own reads of buf nb (tile t-1) done
    __builtin_amdgcn_s_barrier();         // all waves done with buf nb
    STAGE_QKV(2 * t + 2, nb, 0);          // big-tile t+1 (wrap keeps vmcnt uniform)
    STAGE_QKV(2 * t + 3, nb, 1);
    __builtin_amdgcn_s_waitcnt(0x0F78);   // vmcnt(8): big-tile t landed; t+1 (8) in flight
    __builtin_amdgcn_s_barrier();

#pragma unroll
    for (int s = 0; s < 2; ++s) {
      const unsigned short* As = &smem[cur * 16384 + s * 8192];
      const unsigned short* Bs = &smem[cur * 16384 + s * 8192 + 4096];
      short8 af[4], bfr[4];
      for (int mt = 0; mt < 4; ++mt)
        af[mt] = *(const short8*)&As[(wm * 64 + mt * 16 + l16) * 32 + quad * 8];
      for (int nt = 0; nt < 4; ++nt)
        bfr[nt] = *(const short8*)&Bs[(wn * 64 + nt * 16 + l16) * 32 + quad * 8];
      for (int mt = 0; mt < 4; ++mt)
        for (int nt = 0; nt < 4; ++nt)
          acc[mt][nt] = __builtin_amdgcn_mfma_f32_16x16x32_bf16(af[mt], bfr[nt], acc[mt][nt], 0, 0, 0);
    }
  }
#undef STAGE_QKV

  int tt = n0 % 384;        // 0 => QK tile; 128/256 => V tile
  int h = n0 / 384;
  __builtin_amdgcn_s_waitcnt(0x0070);   // drain wrapped prefetch before smem reuse
  __syncthreads();

  if (tt == 0) {
    for (int nt = 0; nt < 4; ++nt) {
      int o = n0 + wn * 64 + nt * 16 + l16;
      float sc = gamma[o] * rsqrtf(var[o] + 1e-5f);
      float bb = beta[o] - mean[o] * sc;
      if (wn == 0) { sc *= 0.18033688f; bb *= 0.18033688f; }  // 0.125 * log2e folded into Q
      int jl = wn * 64 + nt * 16 + l16;
      for (int mt = 0; mt < 4; ++mt)
        for (int r = 0; r < 4; ++r) {
          int ml = wm * 64 + mt * 16 + quad * 4 + r;
          smem[ml * OSTR + jl] = f2bf(acc[mt][nt][r] * sc + bb);
        }
    }
    __syncthreads();
    for (int i = 0; i < 8; ++i) {
      int c = i * 256 + tid;
      int ml = c >> 4, jc = c & 15;
      int m = m0 + ml;
      int b = m / 784, n = m - b * 784;
      uint4 v = *(uint4*)&smem[ml * OSTR + jc * 8];
      int j = jc * 8;
      if (j < 64) *(uint4*)&qo[(((size_t)b * NH + h) * Nseq + n) * KD + j] = v;
      else        *(uint4*)&ko[(((size_t)b * NH + h) * Nseq + n) * KD + (j - 64)] = v;
    }
  } else {
    for (int nt = 0; nt < 4; ++nt) {
      int o = n0 + wn * 64 + nt * 16 + l16;
      float sc = gamma[o] * rsqrtf(var[o] + 1e-5f);
      float bb = beta[o] - mean[o] * sc;
      int cl = wn * 64 + nt * 16 + l16;
      // kv bit2<->bit3 permutation folded into the LDS write index (quad bit swap)
      int qperm = (quad & 1) * 8 + (quad >> 1) * 4;
      for (int mt = 0; mt < 4; ++mt) {
        int ml0 = wm * 64 + mt * 16 + qperm;
        ushort4 pk;
        pk.x = f2bf(acc[mt][nt][0] * sc + bb);
        pk.y = f2bf(acc[mt][nt][1] * sc + bb);
        pk.z = f2bf(acc[mt][nt][2] * sc + bb);
        pk.w = f2bf(acc[mt][nt][3] * sc + bb);
        *(ushort4*)&smem[cl * OSTR + ml0] = pk;
      }
    }
    __syncthreads();
    int cbase = tt - 128;
    for (int i = 0; i < 8; ++i) {
      int c = i * 256 + tid;
      int cl = c >> 4, mc = c & 15;
      int m = m0 + mc * 8;
      int b = m / 784, n = m - b * 784;   // n is a multiple of 8
      uint4 v = *(uint4*)&smem[cl * OSTR + mc * 8];
      *(uint4*)&vto[(((size_t)b * NH + h) * VD + cbase + cl) * Nseq + n] = v;
    }
  }
}

// ---------------- K2: flash attention, 32x32 MFMA, register-resident P ----------------
// UNCHANGED (parked at its co-saturation plateau).
__global__ __launch_bounds__(256, 2) void attn_kernel(
    const unsigned short* __restrict__ qb,   // [bh][784][64] (pre-scaled by 0.125*log2e)
    const unsigned short* __restrict__ kb,   // [bh][784][64]
    const unsigned short* __restrict__ vtb,  // [bh][256][784], n-permuted
    const unsigned short* __restrict__ bias_tab, // [8][784][784] bf16, col-permuted
    unsigned short* __restrict__ U)          // [16*784*2048] bf16 (post-SiLU)
{
  __shared__ unsigned short vt_lds[2 * 256 * 64];  // 64 KB, dbuf, swizzled
  __shared__ unsigned short k_lds[2 * 64 * 64];    // 16 KB, dbuf, swizzled
  int tid = threadIdx.x;
  int wave = tid >> 6, lane = tid & 63;
  int lo = lane & 31, hi = lane >> 5;

  int L = blockIdx.x;
  int xcd = L & 7;
  int s = L >> 3;            // 0..111
  int qp = s % 7;            // 128-row Q group
  int bg = s / 7;            // batch
  int bh = bg * 8 + xcd;     // bh % 8 == h == xcd (head-bias L2 locality)
  int b = bg, h = xcd;

  int qrow_g = qp * 128 + wave * 32 + lo;          // this lane's q row
  int qrow = qrow_g < Nseq ? qrow_g : Nseq - 1;    // clamp dead rows

  int lc = lane >> 3;              // 0..7 (row-sub for glds)
  int lch = (lane & 7) ^ lc;       // swizzled 16B chunk this lane fetches
  int swz = lo & 7;                // read-side swizzle key (== row&7 for all our reads)

  const unsigned short* vsrc = vtb + ((size_t)bh * VD + wave * 64 + lc) * Nseq + lch * 8;
  const unsigned short* ksrc = kb + ((size_t)bh * Nseq + wave * 16 + lc) * KD + lch * 8;
  const unsigned short* brow = bias_tab + (size_t)h * NN + (size_t)qrow * Nseq + 8 * hi;

  // Q fragments first (oldest vm ops)
  short8 qf[4];
  {
    const unsigned short* qp_ = qb + ((size_t)bh * Nseq + qrow) * KD + hi * 8;
#pragma unroll
    for (int kst = 0; kst < 4; ++kst) qf[kst] = *(const short8*)(qp_ + kst * 16);
  }

  // ---- prologue: issue tile 0 (10 glds) + bias tile 0 (4 tracked dwordx4) ----
#pragma unroll
  for (int i = 0; i < 8; ++i) glds16(vsrc + i * (8 * Nseq), &vt_lds[wave * 4096 + i * 512]);
  glds16(ksrc, &k_lds[wave * 1024]);
  glds16(ksrc + 8 * KD, &k_lds[wave * 1024 + 512]);
  u32x4 bbC[4], bbN[4];
#pragma unroll
  for (int g = 0; g < 4; ++g) bbC[g] = *(const u32x4*)(brow + g * 16);

  f32x16 oacc[8];
#pragma unroll
  for (int ct = 0; ct < 8; ++ct) oacc[ct] = (f32x16)0.0f;
  float lsum = 0.0f;

  for (int kt = 0; kt < 13; ++kt) {
    int cur = kt & 1, nb = cur ^ 1;
    __builtin_amdgcn_s_waitcnt(0xC07F);   // lgkmcnt(0) only
    __builtin_amdgcn_s_barrier();
    int ktn = kt + 1; if (ktn >= 13) ktn = 0;   // wrap keeps vmcnt uniform
#pragma unroll
    for (int i = 0; i < 8; ++i)
      glds16(vsrc + i * (8 * Nseq) + ktn * 64, &vt_lds[nb * 16384 + wave * 4096 + i * 512]);
    glds16(ksrc + ktn * (64 * KD), &k_lds[nb * 4096 + wave * 1024]);
    glds16(ksrc + ktn * (64 * KD) + 8 * KD, &k_lds[nb * 4096 + wave * 1024 + 512]);
    // bias for NEXT tile (tracked loads; compiler inserts its own precise wait at use)
#pragma unroll
    for (int g = 0; g < 4; ++g) bbN[g] = *(const u32x4*)(brow + ktn * 64 + g * 16);

    // S^T accumulators initialized with bias — pure reg ops on LAST tile's loads,
    // hoisted before the vmcnt+barrier so the unpack runs under the barrier wait.
    f32x16 st0, st1;
#pragma unroll
    for (int r = 0; r < 16; ++r) {
      unsigned c0 = bbC[r >> 3][(r >> 1) & 3];
      unsigned c1 = bbC[2 + (r >> 3)][(r >> 1) & 3];
      st0[r] = (r & 1) ? bfHI(c0) : bfLO(c0);
      st1[r] = (r & 1) ? bfHI(c1) : bfLO(c1);
    }

    __builtin_amdgcn_s_waitcnt(0x0F7E);   // vmcnt(14): tile kt + bias kt landed; kt+1 in flight
    __builtin_amdgcn_s_barrier();

    const unsigned short* kbuf = &k_lds[cur * 4096];
    const unsigned short* vbuf = &vt_lds[cur * 16384];

    __builtin_amdgcn_s_setprio(1);
#pragma unroll
    for (int kst = 0; kst < 4; ++kst) {
      int ch = ((kst * 2 + hi) ^ swz) * 8;
      short8 kf0 = *(const short8*)&kbuf[lo * 64 + ch];
      short8 kf1 = *(const short8*)&kbuf[(32 + lo) * 64 + ch];
      st0 = __builtin_amdgcn_mfma_f32_32x32x16_bf16(kf0, qf[kst], st0, 0, 0, 0);
      st1 = __builtin_amdgcn_mfma_f32_32x32x16_bf16(kf1, qf[kst], st1, 0, 0, 0);
    }
    __builtin_amdgcn_s_setprio(0);

    // Interleaved softmax + PV per kst-group: exp2(8) -> partial sum -> pack -> 8 MFMAs.
    bool tail = (kt == 12);
    float lp0 = 0.0f, lp1 = 0.0f, lp2 = 0.0f, lp3 = 0.0f;
#pragma unroll
    for (int kst = 0; kst < 4; ++kst) {
      float p0, p1, p2, p3, p4, p5, p6, p7;
      if (kst == 0)      { p0=st0[0]; p1=st0[1]; p2=st0[2];  p3=st0[3];  p4=st0[4];  p5=st0[5];  p6=st0[6];  p7=st0[7];  }
      else if (kst == 1) { p0=st0[8]; p1=st0[9]; p2=st0[10]; p3=st0[11]; p4=st0[12]; p5=st0[13]; p6=st0[14]; p7=st0[15]; }
      else if (kst == 2) { p0=st1[0]; p1=st1[1]; p2=st1[2];  p3=st1[3];  p4=st1[4];  p5=st1[5];  p6=st1[6];  p7=st1[7];  }
      else               { p0=st1[8]; p1=st1[9]; p2=st1[10]; p3=st1[11]; p4=st1[12]; p5=st1[13]; p6=st1[14]; p7=st1[15]; }
      p0 = EXP2(p0); p1 = EXP2(p1); p2 = EXP2(p2); p3 = EXP2(p3);
      p4 = EXP2(p4); p5 = EXP2(p5); p6 = EXP2(p6); p7 = EXP2(p7);
      if (tail && kst > 0) { p0=0; p1=0; p2=0; p3=0; p4=0; p5=0; p6=0; p7=0; }
      float ls = ((p0 + p1) + (p2 + p3)) + ((p4 + p5) + (p6 + p7));
      if (kst == 0) lp0 = ls; else if (kst == 1) lp1 = ls; else if (kst == 2) lp2 = ls; else lp3 = ls;
      unsigned X0, X1, Y0, Y1;
      asm("v_cvt_pk_bf16_f32 %0, %1, %2" : "=v"(X0) : "v"(p0), "v"(p1));
      asm("v_cvt_pk_bf16_f32 %0, %1, %2" : "=v"(X1) : "v"(p2), "v"(p3));
      asm("v_cvt_pk_bf16_f32 %0, %1, %2" : "=v"(Y0) : "v"(p4), "v"(p5));
      asm("v_cvt_pk_bf16_f32 %0, %1, %2" : "=v"(Y1) : "v"(p6), "v"(p7));
      union { unsigned u[4]; short8 s; } pk_;
      pk_.u[0] = X0; pk_.u[1] = X1; pk_.u[2] = Y0; pk_.u[3] = Y1;
      short8 pf = pk_.s;

      int ch = ((kst * 2 + hi) ^ swz) * 8;
      const unsigned short* vr0 = &vbuf[lo * 64 + ch];
      __builtin_amdgcn_s_setprio(1);
#pragma unroll
      for (int ct = 0; ct < 8; ++ct) {
        short8 vf = *(const short8*)&vr0[ct * 2048];
        oacc[ct] = __builtin_amdgcn_mfma_f32_32x32x16_bf16(vf, pf, oacc[ct], 0, 0, 0);
      }
      __builtin_amdgcn_s_setprio(0);
    }
    lsum += (lp0 + lp1) + (lp2 + lp3);

#pragma unroll
    for (int g = 0; g < 4; ++g) bbC[g] = bbN[g];
  }

  __builtin_amdgcn_s_waitcnt(0x0070);   // drain wrapped prefetch before LDS goes out of scope

  // epilogue: row sum across the two kv-halves, SiLU, write
  float tot = lsum + __shfl_xor(lsum, 32);
  float inv = 1.0f / tot;
  if (qrow_g < Nseq) {
    size_t base = ((size_t)b * Nseq + qrow_g) * HV + h * VD;
#pragma unroll
    for (int ct = 0; ct < 8; ++ct)
#pragma unroll
      for (int g2 = 0; g2 < 4; ++g2) {
        ushort4 o4;
#pragma unroll
        for (int r4 = 0; r4 < 4; ++r4) {
          float u = oacc[ct][g2 * 4 + r4] * inv;
          float sg = 1.0f / (1.0f + EXP2(-u * 1.44269504f));
          ((unsigned short*)&o4)[r4] = f2bf(u * sg);
        }
        *(ushort4*)&U[base + ct * 32 + g2 * 8 + hi * 4] = o4;
      }
  }
}

// ---------------- K3: proj GEMM, 128^2 tile, BK=64 (2 sub-steps per sync pair) ----------------
__global__ __launch_bounds__(256, 2) void proj_gemm_kernel(
    const unsigned short* __restrict__ Ubuf,  // [12544][2048]
    const unsigned short* __restrict__ Wp,    // [512][2048]
    const float* __restrict__ gamma, const float* __restrict__ beta,
    const float* __restrict__ mean,  const float* __restrict__ var,
    float* __restrict__ out)                  // [12544][512]
{
  const int K = HV;
  __shared__ unsigned short smem[32768];   // 65536B: 2 bufs x [A0|B0|A1|B1]
  int tid = threadIdx.x;
  int wave = tid >> 6, lane = tid & 63;
  int quad = lane >> 4, l16 = lane & 15;
  int wm = wave >> 1, wn = wave & 1;
  // XCD-chunked bijective swizzle: 392 = 8 * 49
  int bid = blockIdx.x;
  int wgid = (bid & 7) * 49 + (bid >> 3);
  int mB = (wgid % 98) * 128, o0 = (wgid / 98) * 128;

  int srow = wave * 32 + (lane >> 2);
  int sch = (lane & 3) * 8;
  const unsigned short* Ab = Wp + (size_t)(o0 + srow) * K + sch;
  const unsigned short* Bb = Ubuf + (size_t)(mB + srow) * K + sch;

  floatx4 acc[4][4];
  for (int i = 0; i < 4; ++i)
    for (int j = 0; j < 4; ++j) acc[i][j] = (floatx4)0.0f;

#define STAGE_PROJ(kk32, buf, slot) do {                                       \
    int off_ = ((kk32) & 63) * 32;                                             \
    unsigned short* As_ = &smem[(buf) * 16384 + (slot) * 8192 + wave * 1024];  \
    unsigned short* Bs_ = As_ + 4096;                                          \
    glds16(Ab + off_, As_); glds16(Ab + off_ + 16 * K, As_ + 512);             \
    glds16(Bb + off_, Bs_); glds16(Bb + off_ + 16 * K, Bs_ + 512);             \
  } while (0)

  STAGE_PROJ(0, 0, 0);
  STAGE_PROJ(1, 0, 1);

  for (int t = 0; t < 32; ++t) {
    int cur = t & 1, nb = cur ^ 1;
    __builtin_amdgcn_s_waitcnt(0xC07F);
    __builtin_amdgcn_s_barrier();
    STAGE_PROJ(2 * t + 2, nb, 0);
    STAGE_PROJ(2 * t + 3, nb, 1);
    __builtin_amdgcn_s_waitcnt(0x0F78);   // vmcnt(8)
    __builtin_amdgcn_s_barrier();

#pragma unroll
    for (int s = 0; s < 2; ++s) {
      const unsigned short* As = &smem[cur * 16384 + s * 8192];
      const unsigned short* Bs = &smem[cur * 16384 + s * 8192 + 4096];
      short8 af[4], bfr[4];
      for (int mt = 0; mt < 4; ++mt)
        af[mt] = *(const short8*)&As[(wm * 64 + mt * 16 + l16) * 32 + quad * 8];
      for (int nt = 0; nt < 4; ++nt)
        bfr[nt] = *(const short8*)&Bs[(wn * 64 + nt * 16 + l16) * 32 + quad * 8];
      for (int mt = 0; mt < 4; ++mt)
        for (int nt = 0; nt < 4; ++nt)
          acc[mt][nt] = __builtin_amdgcn_mfma_f32_16x16x32_bf16(af[mt], bfr[nt], acc[mt][nt], 0, 0, 0);
    }
  }
#undef STAGE_PROJ
  __builtin_amdgcn_s_waitcnt(0x0070);   // drain wrapped prefetch

  for (int mt = 0; mt < 4; ++mt) {
    int ob = o0 + wm * 64 + mt * 16 + quad * 4;
    float4 g = *(const float4*)&gamma[ob];
    float4 vr = *(const float4*)&var[ob];
    float4 mn = *(const float4*)&mean[ob];
    float4 bt = *(const float4*)&beta[ob];
    float sc0 = g.x * rsqrtf(vr.x + 1e-5f), bb0 = bt.x - mn.x * sc0;
    float sc1 = g.y * rsqrtf(vr.y + 1e-5f), bb1 = bt.y - mn.y * sc1;
    float sc2 = g.z * rsqrtf(vr.z + 1e-5f), bb2 = bt.z - mn.z * sc2;
    float sc3 = g.w * rsqrtf(vr.w + 1e-5f), bb3 = bt.w - mn.w * sc3;
    for (int nt = 0; nt < 4; ++nt) {
      int m = mB + wn * 64 + nt * 16 + l16;
      float4 v;
      v.x = acc[mt][nt][0] * sc0 + bb0;
      v.y = acc[mt][nt][1] * sc1 + bb1;
      v.z = acc[mt][nt][2] * sc2 + bb2;
      v.w = acc[mt][nt][3] * sc3 + bb3;
      *(float4*)&out[(size_t)m * DIM + ob] = v;
    }
  }
}

// ---------------- launch ----------------
extern "C" void kernel_launch(void* const* d_in, const int* in_sizes, int n_in,
                              void* d_out, int out_size, void* d_ws, size_t ws_size,
                              hipStream_t stream) {
  const float* x          = (const float*)d_in[0];
  const float* qkv_w      = (const float*)d_in[1];
  const float* qkv_gamma  = (const float*)d_in[2];
  const float* qkv_beta   = (const float*)d_in[3];
  const float* qkv_mean   = (const float*)d_in[4];
  const float* qkv_var    = (const float*)d_in[5];
  const float* att_biases = (const float*)d_in[6];
  const float* proj_w     = (const float*)d_in[7];
  const float* proj_gamma = (const float*)d_in[8];
  const float* proj_beta  = (const float*)d_in[9];
  const float* proj_mean  = (const float*)d_in[10];
  const float* proj_var   = (const float*)d_in[11];
  const int*   bias_idxs  = (const int*)d_in[12];
  float* out = (float*)d_out;

  char* ws = (char*)d_ws;
  unsigned short* xb  = (unsigned short*)(ws);                 // 12544*512 (12.85 MB)
  unsigned short* bias_tab = (unsigned short*)(ws);            // 8*784*784 bf16 — aliases xb (dead after qkv_gemm)
  unsigned short* wq  = (unsigned short*)(ws + 12845056);      // 3072*512
  unsigned short* wp  = (unsigned short*)(ws + 15990784);      // 512*2048
  unsigned short* qo  = (unsigned short*)(ws + 18087936);      // 16*8*784*64
  unsigned short* ko  = (unsigned short*)(ws + 30932992);      // 16*8*784*64
  unsigned short* vto = (unsigned short*)(ws + 43778048);      // 16*8*256*784
  unsigned short* Ub  = (unsigned short*)(ws + 95158272);      // 12544*2048
  // total: 146538496 bytes

  {
    int n4 = N4X + N4Q + N4P;
    cvt_all_kernel<<<(n4 + 255) / 256, 256, 0, stream>>>(x, qkv_w, proj_w, xb, wq, wp);
  }

  qkv_gemm_kernel<<<2352, 256, 0, stream>>>(
      xb, wq, qkv_gamma, qkv_beta, qkv_mean, qkv_var, qo, ko, vto);

  bias_pre_kernel<<<(NN + 255) / 256, 256, 0, stream>>>(att_biases, bias_idxs, bias_tab);

  attn_kernel<<<7 * Bsz * NH, 256, 0, stream>>>(qo, ko, vto, bias_tab, Ub);

  proj_gemm_kernel<<<392, 256, 0, stream>>>(
      Ub, wp, proj_gamma, proj_beta, proj_mean, proj_var, out);
}

// Round 11
// 293.882 us; speedup vs baseline: 1.0324x; 1.0002x over previous
//
#include <hip/hip_runtime.h>

// Problem constants
#define Bsz 16
#define Nseq 784
#define DIM 512
#define NH 8
#define KD 64
#define VD 256
#define QKV_OUT 3072   // (2*64+256)*8
#define HV 2048        // NH*VD
#define NN 614656      // 784*784

typedef __attribute__((ext_vector_type(8))) short short8;
typedef __attribute__((ext_vector_type(4))) float floatx4;
typedef __attribute__((ext_vector_type(16))) float f32x16;
typedef __attribute__((ext_vector_type(4))) unsigned u32x4;

#define OSTR 136  // LDS row stride for qkv epilogue tile (bf16): 272B, 16B-aligned

#if __has_builtin(__builtin_amdgcn_exp2f)
#define EXP2(x) __builtin_amdgcn_exp2f(x)
#else
#define EXP2(x) exp2f(x)
#endif

__device__ __forceinline__ unsigned short f2bf(float f) {
  union { float f; unsigned u; } v; v.f = f;
  unsigned r = v.u + 0x7fffu + ((v.u >> 16) & 1u);
  return (unsigned short)(r >> 16);
}
__device__ __forceinline__ float bfLO(unsigned u) {
  union { unsigned u; float f; } v; v.u = u << 16; return v.f;
}
__device__ __forceinline__ float bfHI(unsigned u) {
  union { unsigned u; float f; } v; v.u = u & 0xffff0000u; return v.f;
}

// async global->LDS, 16B per lane; LDS dst = wave-uniform base + lane*16
__device__ __forceinline__ void glds16(const unsigned short* g, unsigned short* l) {
  __builtin_amdgcn_global_load_lds(
      (const __attribute__((address_space(1))) void*)g,
      (__attribute__((address_space(3))) void*)l, 16, 0, 0);
}

// ---------------- K0: fused fp32 -> bf16 convert (x, qkv_w, proj_w) ----------------
#define N4X 1605632   // x float4s
#define N4Q 393216    // qkv_w float4s
#define N4P 262144    // proj_w float4s
__global__ void cvt_all_kernel(const float* __restrict__ x,
                               const float* __restrict__ qw,
                               const float* __restrict__ pw,
                               unsigned short* __restrict__ xb,
                               unsigned short* __restrict__ wq,
                               unsigned short* __restrict__ wp) {
  int i = blockIdx.x * 256 + threadIdx.x;
  const float4* s; ushort4* d; int off;
  if (i < N4X)              { s = (const float4*)x;  d = (ushort4*)xb; off = i; }
  else if (i < N4X + N4Q)   { s = (const float4*)qw; d = (ushort4*)wq; off = i - N4X; }
  else if (i < N4X + N4Q + N4P) { s = (const float4*)pw; d = (ushort4*)wp; off = i - N4X - N4Q; }
  else return;
  float4 v = s[off];
  ushort4 o;
  o.x = f2bf(v.x); o.y = f2bf(v.y); o.z = f2bf(v.z); o.w = f2bf(v.w);
  d[off] = o;
}

// ---------------- K0b: bias table [8][784][784] bf16, log2e-folded, columns bit2<->bit3 permuted ----------------
__global__ void bias_pre_kernel(const float* __restrict__ biases,
                                const int* __restrict__ bias_idxs,
                                unsigned short* __restrict__ bias_tab) {
  int t = blockIdx.x * 256 + threadIdx.x;
  if (t >= NN) return;
  int idx = bias_idxs[t];
  // 784 % 16 == 0, so swapping bits 2,3 of the flat index permutes within the column part
  int p = (t & ~12) | ((t & 4) << 1) | ((t & 8) >> 1);
  for (int h = 0; h < NH; ++h)
    bias_tab[(size_t)h * NN + p] = f2bf(1.44269504f * biases[h * Nseq + idx]);
}

// ---------------- K1: QKV GEMM, 128^2 tile, CANONICAL single-barrier 2-phase ----------------
// R10 post-mortem: depth/pair-count/occupancy/L2/tile all null -> the convoy structure
// itself (2 barriers + 2 waits per k-step, loads covered only by the inter-barrier gap)
// is the suspect. This is the guide's verified minimum-2-phase recipe (m248: 655-682 TF):
//   STAGE(next) -> ds_read(cur)+MFMA (data-dep lgkm) -> vmcnt(0) -> ONE barrier.
// Loads get the whole compute phase to land; 1 barrier/k-step; staging LDS 32KB ->
// 4 blocks/CU ((256,4), 16 waves) for cross-block overlap.
__global__ __launch_bounds__(256, 4) void qkv_gemm_kernel(
    const unsigned short* __restrict__ A,
    const unsigned short* __restrict__ Bw,
    const float* __restrict__ gamma, const float* __restrict__ beta,
    const float* __restrict__ mean,  const float* __restrict__ var,
    unsigned short* __restrict__ qo,   // [B,H,N,64] (pre-scaled by 0.125*log2e)
    unsigned short* __restrict__ ko,   // [B,H,N,64]
    unsigned short* __restrict__ vto)  // [B,H,256,N] with n-dim bit2<->bit3 permuted
{
  const int K = DIM;
  __shared__ unsigned short smem[17408];  // 34816B: staging 2x8192 shorts; epilogue arena aliases
  int tid = threadIdx.x;
  int wave = tid >> 6, lane = tid & 63;
  int quad = lane >> 4, l16 = lane & 15;
  int wm = wave >> 1, wn = wave & 1;
  // XCD-chunked bijective swizzle: 2352 = 8 * 294
  int bid = blockIdx.x;
  int wgid = (bid & 7) * 294 + (bid >> 3);
  int m0 = (wgid / 24) * 128, n0 = (wgid % 24) * 128;

  int srow = wave * 32 + (lane >> 2);
  int sch = (lane & 3) * 8;
  const unsigned short* Ab = A + (size_t)(m0 + srow) * K + sch;
  const unsigned short* Bb = Bw + (size_t)(n0 + srow) * K + sch;

  floatx4 acc[4][4];
  for (int i = 0; i < 4; ++i)
    for (int j = 0; j < 4; ++j) acc[i][j] = (floatx4)0.0f;

#define STAGE_QKV(kk, buf) do {                                          \
    int off_ = ((kk) & 15) * 32;                                         \
    unsigned short* As_ = &smem[(buf) * 8192 + wave * 1024];             \
    unsigned short* Bs_ = As_ + 4096;                                    \
    glds16(Ab + off_, As_); glds16(Ab + off_ + 16 * K, As_ + 512);       \
    glds16(Bb + off_, Bs_); glds16(Bb + off_ + 16 * K, Bs_ + 512);       \
  } while (0)

  // prologue: stage k=0 -> buf0, wait, barrier
  STAGE_QKV(0, 0);
  __builtin_amdgcn_s_waitcnt(0x0F70);   // vmcnt(0)
  __builtin_amdgcn_s_barrier();

  for (int k = 0; k < 16; ++k) {
    int cur = k & 1, nb = cur ^ 1;
    STAGE_QKV((k + 1) & 15, nb);        // issue next-tile loads FIRST (wrap keeps uniform)

    const unsigned short* As = &smem[cur * 8192];
    const unsigned short* Bs = &smem[cur * 8192 + 4096];
    short8 af[4], bfr[4];
    for (int mt = 0; mt < 4; ++mt)
      af[mt] = *(const short8*)&As[(wm * 64 + mt * 16 + l16) * 32 + quad * 8];
    for (int nt = 0; nt < 4; ++nt)
      bfr[nt] = *(const short8*)&Bs[(wn * 64 + nt * 16 + l16) * 32 + quad * 8];
    __builtin_amdgcn_s_setprio(1);
    for (int mt = 0; mt < 4; ++mt)
      for (int nt = 0; nt < 4; ++nt)
        acc[mt][nt] = __builtin_amdgcn_mfma_f32_16x16x32_bf16(af[mt], bfr[nt], acc[mt][nt], 0, 0, 0);
    __builtin_amdgcn_s_setprio(0);

    __builtin_amdgcn_s_waitcnt(0x0F70); // vmcnt(0): next tile landed (covered by compute)
    __builtin_amdgcn_s_barrier();       // reads of cur complete (MFMA dep) -> safe to reuse
  }
#undef STAGE_QKV

  int tt = n0 % 384;        // 0 => QK tile; 128/256 => V tile
  int h = n0 / 384;
  __builtin_amdgcn_s_waitcnt(0x0070);   // belt-and-braces drain before smem reuse
  __syncthreads();

  if (tt == 0) {
    for (int nt = 0; nt < 4; ++nt) {
      int o = n0 + wn * 64 + nt * 16 + l16;
      float sc = gamma[o] * rsqrtf(var[o] + 1e-5f);
      float bb = beta[o] - mean[o] * sc;
      if (wn == 0) { sc *= 0.18033688f; bb *= 0.18033688f; }  // 0.125 * log2e folded into Q
      int jl = wn * 64 + nt * 16 + l16;
      for (int mt = 0; mt < 4; ++mt)
        for (int r = 0; r < 4; ++r) {
          int ml = wm * 64 + mt * 16 + quad * 4 + r;
          smem[ml * OSTR + jl] = f2bf(acc[mt][nt][r] * sc + bb);
        }
    }
    __syncthreads();
    for (int i = 0; i < 8; ++i) {
      int c = i * 256 + tid;
      int ml = c >> 4, jc = c & 15;
      int m = m0 + ml;
      int b = m / 784, n = m - b * 784;
      uint4 v = *(uint4*)&smem[ml * OSTR + jc * 8];
      int j = jc * 8;
      if (j < 64) *(uint4*)&qo[(((size_t)b * NH + h) * Nseq + n) * KD + j] = v;
      else        *(uint4*)&ko[(((size_t)b * NH + h) * Nseq + n) * KD + (j - 64)] = v;
    }
  } else {
    for (int nt = 0; nt < 4; ++nt) {
      int o = n0 + wn * 64 + nt * 16 + l16;
      float sc = gamma[o] * rsqrtf(var[o] + 1e-5f);
      float bb = beta[o] - mean[o] * sc;
      int cl = wn * 64 + nt * 16 + l16;
      // kv bit2<->bit3 permutation folded into the LDS write index (quad bit swap)
      int qperm = (quad & 1) * 8 + (quad >> 1) * 4;
      for (int mt = 0; mt < 4; ++mt) {
        int ml0 = wm * 64 + mt * 16 + qperm;
        ushort4 pk;
        pk.x = f2bf(acc[mt][nt][0] * sc + bb);
        pk.y = f2bf(acc[mt][nt][1] * sc + bb);
        pk.z = f2bf(acc[mt][nt][2] * sc + bb);
        pk.w = f2bf(acc[mt][nt][3] * sc + bb);
        *(ushort4*)&smem[cl * OSTR + ml0] = pk;
      }
    }
    __syncthreads();
    int cbase = tt - 128;
    for (int i = 0; i < 8; ++i) {
      int c = i * 256 + tid;
      int cl = c >> 4, mc = c & 15;
      int m = m0 + mc * 8;
      int b = m / 784, n = m - b * 784;   // n is a multiple of 8
      uint4 v = *(uint4*)&smem[cl * OSTR + mc * 8];
      *(uint4*)&vto[(((size_t)b * NH + h) * VD + cbase + cl) * Nseq + n] = v;
    }
  }
}

// ---------------- K2: flash attention, 32x32 MFMA, register-resident P ----------------
// UNCHANGED (parked at its co-saturation plateau).
__global__ __launch_bounds__(256, 2) void attn_kernel(
    const unsigned short* __restrict__ qb,   // [bh][784][64] (pre-scaled by 0.125*log2e)
    const unsigned short* __restrict__ kb,   // [bh][784][64]
    const unsigned short* __restrict__ vtb,  // [bh][256][784], n-permuted
    const unsigned short* __restrict__ bias_tab, // [8][784][784] bf16, col-permuted
    unsigned short* __restrict__ U)          // [16*784*2048] bf16 (post-SiLU)
{
  __shared__ unsigned short vt_lds[2 * 256 * 64];  // 64 KB, dbuf, swizzled
  __shared__ unsigned short k_lds[2 * 64 * 64];    // 16 KB, dbuf, swizzled
  int tid = threadIdx.x;
  int wave = tid >> 6, lane = tid & 63;
  int lo = lane & 31, hi = lane >> 5;

  int L = blockIdx.x;
  int xcd = L & 7;
  int s = L >> 3;            // 0..111
  int qp = s % 7;            // 128-row Q group
  int bg = s / 7;            // batch
  int bh = bg * 8 + xcd;     // bh % 8 == h == xcd (head-bias L2 locality)
  int b = bg, h = xcd;

  int qrow_g = qp * 128 + wave * 32 + lo;          // this lane's q row
  int qrow = qrow_g < Nseq ? qrow_g : Nseq - 1;    // clamp dead rows

  int lc = lane >> 3;              // 0..7 (row-sub for glds)
  int lch = (lane & 7) ^ lc;       // swizzled 16B chunk this lane fetches
  int swz = lo & 7;                // read-side swizzle key (== row&7 for all our reads)

  const unsigned short* vsrc = vtb + ((size_t)bh * VD + wave * 64 + lc) * Nseq + lch * 8;
  const unsigned short* ksrc = kb + ((size_t)bh * Nseq + wave * 16 + lc) * KD + lch * 8;
  const unsigned short* brow = bias_tab + (size_t)h * NN + (size_t)qrow * Nseq + 8 * hi;

  // Q fragments first (oldest vm ops)
  short8 qf[4];
  {
    const unsigned short* qp_ = qb + ((size_t)bh * Nseq + qrow) * KD + hi * 8;
#pragma unroll
    for (int kst = 0; kst < 4; ++kst) qf[kst] = *(const short8*)(qp_ + kst * 16);
  }

  // ---- prologue: issue tile 0 (10 glds) + bias tile 0 (4 tracked dwordx4) ----
#pragma unroll
  for (int i = 0; i < 8; ++i) glds16(vsrc + i * (8 * Nseq), &vt_lds[wave * 4096 + i * 512]);
  glds16(ksrc, &k_lds[wave * 1024]);
  glds16(ksrc + 8 * KD, &k_lds[wave * 1024 + 512]);
  u32x4 bbC[4], bbN[4];
#pragma unroll
  for (int g = 0; g < 4; ++g) bbC[g] = *(const u32x4*)(brow + g * 16);

  f32x16 oacc[8];
#pragma unroll
  for (int ct = 0; ct < 8; ++ct) oacc[ct] = (f32x16)0.0f;
  float lsum = 0.0f;

  for (int kt = 0; kt < 13; ++kt) {
    int cur = kt & 1, nb = cur ^ 1;
    __builtin_amdgcn_s_waitcnt(0xC07F);   // lgkmcnt(0) only
    __builtin_amdgcn_s_barrier();
    int ktn = kt + 1; if (ktn >= 13) ktn = 0;   // wrap keeps vmcnt uniform
#pragma unroll
    for (int i = 0; i < 8; ++i)
      glds16(vsrc + i * (8 * Nseq) + ktn * 64, &vt_lds[nb * 16384 + wave * 4096 + i * 512]);
    glds16(ksrc + ktn * (64 * KD), &k_lds[nb * 4096 + wave * 1024]);
    glds16(ksrc + ktn * (64 * KD) + 8 * KD, &k_lds[nb * 4096 + wave * 1024 + 512]);
    // bias for NEXT tile (tracked loads; compiler inserts its own precise wait at use)
#pragma unroll
    for (int g = 0; g < 4; ++g) bbN[g] = *(const u32x4*)(brow + ktn * 64 + g * 16);

    // S^T accumulators initialized with bias — pure reg ops on LAST tile's loads,
    // hoisted before the vmcnt+barrier so the unpack runs under the barrier wait.
    f32x16 st0, st1;
#pragma unroll
    for (int r = 0; r < 16; ++r) {
      unsigned c0 = bbC[r >> 3][(r >> 1) & 3];
      unsigned c1 = bbC[2 + (r >> 3)][(r >> 1) & 3];
      st0[r] = (r & 1) ? bfHI(c0) : bfLO(c0);
      st1[r] = (r & 1) ? bfHI(c1) : bfLO(c1);
    }

    __builtin_amdgcn_s_waitcnt(0x0F7E);   // vmcnt(14): tile kt + bias kt landed; kt+1 in flight
    __builtin_amdgcn_s_barrier();

    const unsigned short* kbuf = &k_lds[cur * 4096];
    const unsigned short* vbuf = &vt_lds[cur * 16384];

    __builtin_amdgcn_s_setprio(1);
#pragma unroll
    for (int kst = 0; kst < 4; ++kst) {
      int ch = ((kst * 2 + hi) ^ swz) * 8;
      short8 kf0 = *(const short8*)&kbuf[lo * 64 + ch];
      short8 kf1 = *(const short8*)&kbuf[(32 + lo) * 64 + ch];
      st0 = __builtin_amdgcn_mfma_f32_32x32x16_bf16(kf0, qf[kst], st0, 0, 0, 0);
      st1 = __builtin_amdgcn_mfma_f32_32x32x16_bf16(kf1, qf[kst], st1, 0, 0, 0);
    }
    __builtin_amdgcn_s_setprio(0);

    // Interleaved softmax + PV per kst-group: exp2(8) -> partial sum -> pack -> 8 MFMAs.
    bool tail = (kt == 12);
    float lp0 = 0.0f, lp1 = 0.0f, lp2 = 0.0f, lp3 = 0.0f;
#pragma unroll
    for (int kst = 0; kst < 4; ++kst) {
      float p0, p1, p2, p3, p4, p5, p6, p7;
      if (kst == 0)      { p0=st0[0]; p1=st0[1]; p2=st0[2];  p3=st0[3];  p4=st0[4];  p5=st0[5];  p6=st0[6];  p7=st0[7];  }
      else if (kst == 1) { p0=st0[8]; p1=st0[9]; p2=st0[10]; p3=st0[11]; p4=st0[12]; p5=st0[13]; p6=st0[14]; p7=st0[15]; }
      else if (kst == 2) { p0=st1[0]; p1=st1[1]; p2=st1[2];  p3=st1[3];  p4=st1[4];  p5=st1[5];  p6=st1[6];  p7=st1[7];  }
      else               { p0=st1[8]; p1=st1[9]; p2=st1[10]; p3=st1[11]; p4=st1[12]; p5=st1[13]; p6=st1[14]; p7=st1[15]; }
      p0 = EXP2(p0); p1 = EXP2(p1); p2 = EXP2(p2); p3 = EXP2(p3);
      p4 = EXP2(p4); p5 = EXP2(p5); p6 = EXP2(p6); p7 = EXP2(p7);
      if (tail && kst > 0) { p0=0; p1=0; p2=0; p3=0; p4=0; p5=0; p6=0; p7=0; }
      float ls = ((p0 + p1) + (p2 + p3)) + ((p4 + p5) + (p6 + p7));
      if (kst == 0) lp0 = ls; else if (kst == 1) lp1 = ls; else if (kst == 2) lp2 = ls; else lp3 = ls;
      unsigned X0, X1, Y0, Y1;
      asm("v_cvt_pk_bf16_f32 %0, %1, %2" : "=v"(X0) : "v"(p0), "v"(p1));
      asm("v_cvt_pk_bf16_f32 %0, %1, %2" : "=v"(X1) : "v"(p2), "v"(p3));
      asm("v_cvt_pk_bf16_f32 %0, %1, %2" : "=v"(Y0) : "v"(p4), "v"(p5));
      asm("v_cvt_pk_bf16_f32 %0, %1, %2" : "=v"(Y1) : "v"(p6), "v"(p7));
      union { unsigned u[4]; short8 s; } pk_;
      pk_.u[0] = X0; pk_.u[1] = X1; pk_.u[2] = Y0; pk_.u[3] = Y1;
      short8 pf = pk_.s;

      int ch = ((kst * 2 + hi) ^ swz) * 8;
      const unsigned short* vr0 = &vbuf[lo * 64 + ch];
      __builtin_amdgcn_s_setprio(1);
#pragma unroll
      for (int ct = 0; ct < 8; ++ct) {
        short8 vf = *(const short8*)&vr0[ct * 2048];
        oacc[ct] = __builtin_amdgcn_mfma_f32_32x32x16_bf16(vf, pf, oacc[ct], 0, 0, 0);
      }
      __builtin_amdgcn_s_setprio(0);
    }
    lsum += (lp0 + lp1) + (lp2 + lp3);

#pragma unroll
    for (int g = 0; g < 4; ++g) bbC[g] = bbN[g];
  }

  __builtin_amdgcn_s_waitcnt(0x0070);   // drain wrapped prefetch before LDS goes out of scope

  // epilogue: row sum across the two kv-halves, SiLU, write
  float tot = lsum + __shfl_xor(lsum, 32);
  float inv = 1.0f / tot;
  if (qrow_g < Nseq) {
    size_t base = ((size_t)b * Nseq + qrow_g) * HV + h * VD;
#pragma unroll
    for (int ct = 0; ct < 8; ++ct)
#pragma unroll
      for (int g2 = 0; g2 < 4; ++g2) {
        ushort4 o4;
#pragma unroll
        for (int r4 = 0; r4 < 4; ++r4) {
          float u = oacc[ct][g2 * 4 + r4] * inv;
          float sg = 1.0f / (1.0f + EXP2(-u * 1.44269504f));
          ((unsigned short*)&o4)[r4] = f2bf(u * sg);
        }
        *(ushort4*)&U[base + ct * 32 + g2 * 8 + hi * 4] = o4;
      }
  }
}

// ---------------- K3: proj GEMM, 128^2 tile, CANONICAL single-barrier 2-phase ----------------
__global__ __launch_bounds__(256, 4) void proj_gemm_kernel(
    const unsigned short* __restrict__ Ubuf,  // [12544][2048]
    const unsigned short* __restrict__ Wp,    // [512][2048]
    const float* __restrict__ gamma, const float* __restrict__ beta,
    const float* __restrict__ mean,  const float* __restrict__ var,
    float* __restrict__ out)                  // [12544][512]
{
  const int K = HV;
  __shared__ unsigned short smem[16384];   // 32KB: 2 bufs x [A 4096 | B 4096] shorts
  int tid = threadIdx.x;
  int wave = tid >> 6, lane = tid & 63;
  int quad = lane >> 4, l16 = lane & 15;
  int wm = wave >> 1, wn = wave & 1;
  // XCD-chunked bijective swizzle: 392 = 8 * 49
  int bid = blockIdx.x;
  int wgid = (bid & 7) * 49 + (bid >> 3);
  int mB = (wgid % 98) * 128, o0 = (wgid / 98) * 128;

  int srow = wave * 32 + (lane >> 2);
  int sch = (lane & 3) * 8;
  const unsigned short* Ab = Wp + (size_t)(o0 + srow) * K + sch;
  const unsigned short* Bb = Ubuf + (size_t)(mB + srow) * K + sch;

  floatx4 acc[4][4];
  for (int i = 0; i < 4; ++i)
    for (int j = 0; j < 4; ++j) acc[i][j] = (floatx4)0.0f;

#define STAGE_PROJ(kk, buf) do {                                         \
    int off_ = ((kk) & 63) * 32;                                         \
    unsigned short* As_ = &smem[(buf) * 8192 + wave * 1024];             \
    unsigned short* Bs_ = As_ + 4096;                                    \
    glds16(Ab + off_, As_); glds16(Ab + off_ + 16 * K, As_ + 512);       \
    glds16(Bb + off_, Bs_); glds16(Bb + off_ + 16 * K, Bs_ + 512);       \
  } while (0)

  STAGE_PROJ(0, 0);
  __builtin_amdgcn_s_waitcnt(0x0F70);   // vmcnt(0)
  __builtin_amdgcn_s_barrier();

  for (int k = 0; k < 64; ++k) {
    int cur = k & 1, nb = cur ^ 1;
    STAGE_PROJ((k + 1) & 63, nb);       // issue next-tile loads FIRST

    const unsigned short* As = &smem[cur * 8192];
    const unsigned short* Bs = &smem[cur * 8192 + 4096];
    short8 af[4], bfr[4];
    for (int mt = 0; mt < 4; ++mt)
      af[mt] = *(const short8*)&As[(wm * 64 + mt * 16 + l16) * 32 + quad * 8];
    for (int nt = 0; nt < 4; ++nt)
      bfr[nt] = *(const short8*)&Bs[(wn * 64 + nt * 16 + l16) * 32 + quad * 8];
    __builtin_amdgcn_s_setprio(1);
    for (int mt = 0; mt < 4; ++mt)
      for (int nt = 0; nt < 4; ++nt)
        acc[mt][nt] = __builtin_amdgcn_mfma_f32_16x16x32_bf16(af[mt], bfr[nt], acc[mt][nt], 0, 0, 0);
    __builtin_amdgcn_s_setprio(0);

    __builtin_amdgcn_s_waitcnt(0x0F70); // vmcnt(0): next tile landed
    __builtin_amdgcn_s_barrier();
  }
#undef STAGE_PROJ
  __builtin_amdgcn_s_waitcnt(0x0070);   // final drain (free: loop already drained)

  for (int mt = 0; mt < 4; ++mt) {
    int ob = o0 + wm * 64 + mt * 16 + quad * 4;
    float4 g = *(const float4*)&gamma[ob];
    float4 vr = *(const float4*)&var[ob];
    float4 mn = *(const float4*)&mean[ob];
    float4 bt = *(const float4*)&beta[ob];
    float sc0 = g.x * rsqrtf(vr.x + 1e-5f), bb0 = bt.x - mn.x * sc0;
    float sc1 = g.y * rsqrtf(vr.y + 1e-5f), bb1 = bt.y - mn.y * sc1;
    float sc2 = g.z * rsqrtf(vr.z + 1e-5f), bb2 = bt.z - mn.z * sc2;
    float sc3 = g.w * rsqrtf(vr.w + 1e-5f), bb3 = bt.w - mn.w * sc3;
    for (int nt = 0; nt < 4; ++nt) {
      int m = mB + wn * 64 + nt * 16 + l16;
      float4 v;
      v.x = acc[mt][nt][0] * sc0 + bb0;
      v.y = acc[mt][nt][1] * sc1 + bb1;
      v.z = acc[mt][nt][2] * sc2 + bb2;
      v.w = acc[mt][nt][3] * sc3 + bb3;
      *(float4*)&out[(size_t)m * DIM + ob] = v;
    }
  }
}

// ---------------- launch ----------------
extern "C" void kernel_launch(void* const* d_in, const int* in_sizes, int n_in,
                              void* d_out, int out_size, void* d_ws, size_t ws_size,
                              hipStream_t stream) {
  const float* x          = (const float*)d_in[0];
  const float* qkv_w      = (const float*)d_in[1];
  const float* qkv_gamma  = (const float*)d_in[2];
  const float* qkv_beta   = (const float*)d_in[3];
  const float* qkv_mean   = (const float*)d_in[4];
  const float* qkv_var    = (const float*)d_in[5];
  const float* att_biases = (const float*)d_in[6];
  const float* proj_w     = (const float*)d_in[7];
  const float* proj_gamma = (const float*)d_in[8];
  const float* proj_beta  = (const float*)d_in[9];
  const float* proj_mean  = (const float*)d_in[10];
  const float* proj_var   = (const float*)d_in[11];
  const int*   bias_idxs  = (const int*)d_in[12];
  float* out = (float*)d_out;

  char* ws = (char*)d_ws;
  unsigned short* xb  = (unsigned short*)(ws);                 // 12544*512 (12.85 MB)
  unsigned short* bias_tab = (unsigned short*)(ws);            // 8*784*784 bf16 — aliases xb (dead after qkv_gemm)
  unsigned short* wq  = (unsigned short*)(ws + 12845056);      // 3072*512
  unsigned short* wp  = (unsigned short*)(ws + 15990784);      // 512*2048
  unsigned short* qo  = (unsigned short*)(ws + 18087936);      // 16*8*784*64
  unsigned short* ko  = (unsigned short*)(ws + 30932992);      // 16*8*784*64
  unsigned short* vto = (unsigned short*)(ws + 43778048);      // 16*8*256*784
  unsigned short* Ub  = (unsigned short*)(ws + 95158272);      // 12544*2048
  // total: 146538496 bytes

  {
    int n4 = N4X + N4Q + N4P;
    cvt_all_kernel<<<(n4 + 255) / 256, 256, 0, stream>>>(x, qkv_w, proj_w, xb, wq, wp);
  }

  qkv_gemm_kernel<<<2352, 256, 0, stream>>>(
      xb, wq, qkv_gamma, qkv_beta, qkv_mean, qkv_var, qo, ko, vto);

  bias_pre_kernel<<<(NN + 255) / 256, 256, 0, stream>>>(att_biases, bias_idxs, bias_tab);

  attn_kernel<<<7 * Bsz * NH, 256, 0, stream>>>(qo, ko, vto, bias_tab, Ub);

  proj_gemm_kernel<<<392, 256, 0, stream>>>(
      Ub, wp, proj_gamma, proj_beta, proj_mean, proj_var, out);
}

// Round 12
// 291.365 us; speedup vs baseline: 1.0413x; 1.0086x over previous
//
#include <hip/hip_runtime.h>

// Problem constants
#define Bsz 16
#define Nseq 784
#define DIM 512
#define NH 8
#define KD 64
#define VD 256
#define QKV_OUT 3072   // (2*64+256)*8
#define HV 2048        // NH*VD
#define NN 614656      // 784*784

typedef __attribute__((ext_vector_type(8))) short short8;
typedef __attribute__((ext_vector_type(4))) float floatx4;
typedef __attribute__((ext_vector_type(16))) float f32x16;
typedef __attribute__((ext_vector_type(4))) unsigned u32x4;

#define OSTR 136  // LDS row stride for qkv epilogue tile (bf16): 272B, 16B-aligned

#if __has_builtin(__builtin_amdgcn_exp2f)
#define EXP2(x) __builtin_amdgcn_exp2f(x)
#else
#define EXP2(x) exp2f(x)
#endif

__device__ __forceinline__ unsigned short f2bf(float f) {
  union { float f; unsigned u; } v; v.f = f;
  unsigned r = v.u + 0x7fffu + ((v.u >> 16) & 1u);
  return (unsigned short)(r >> 16);
}
__device__ __forceinline__ float bfLO(unsigned u) {
  union { unsigned u; float f; } v; v.u = u << 16; return v.f;
}
__device__ __forceinline__ float bfHI(unsigned u) {
  union { unsigned u; float f; } v; v.u = u & 0xffff0000u; return v.f;
}

// async global->LDS, 16B per lane; LDS dst = wave-uniform base + lane*16
__device__ __forceinline__ void glds16(const unsigned short* g, unsigned short* l) {
  __builtin_amdgcn_global_load_lds(
      (const __attribute__((address_space(1))) void*)g,
      (__attribute__((address_space(3))) void*)l, 16, 0, 0);
}

// ---------------- K0: fused fp32 -> bf16 convert (x, qkv_w, proj_w) ----------------
#define N4X 1605632   // x float4s
#define N4Q 393216    // qkv_w float4s
#define N4P 262144    // proj_w float4s
__global__ void cvt_all_kernel(const float* __restrict__ x,
                               const float* __restrict__ qw,
                               const float* __restrict__ pw,
                               unsigned short* __restrict__ xb,
                               unsigned short* __restrict__ wq,
                               unsigned short* __restrict__ wp) {
  int i = blockIdx.x * 256 + threadIdx.x;
  const float4* s; ushort4* d; int off;
  if (i < N4X)              { s = (const float4*)x;  d = (ushort4*)xb; off = i; }
  else if (i < N4X + N4Q)   { s = (const float4*)qw; d = (ushort4*)wq; off = i - N4X; }
  else if (i < N4X + N4Q + N4P) { s = (const float4*)pw; d = (ushort4*)wp; off = i - N4X - N4Q; }
  else return;
  float4 v = s[off];
  ushort4 o;
  o.x = f2bf(v.x); o.y = f2bf(v.y); o.z = f2bf(v.z); o.w = f2bf(v.w);
  d[off] = o;
}

// ---------------- K0b: bias table [8][784][784] bf16, log2e-folded, columns bit2<->bit3 permuted ----------------
__global__ void bias_pre_kernel(const float* __restrict__ biases,
                                const int* __restrict__ bias_idxs,
                                unsigned short* __restrict__ bias_tab) {
  int t = blockIdx.x * 256 + threadIdx.x;
  if (t >= NN) return;
  int idx = bias_idxs[t];
  // 784 % 16 == 0, so swapping bits 2,3 of the flat index permutes within the column part
  int p = (t & ~12) | ((t & 4) << 1) | ((t & 8) >> 1);
  for (int h = 0; h < NH; ++h)
    bias_tab[(size_t)h * NN + p] = f2bf(1.44269504f * biases[h * Nseq + idx]);
}

// ---------------- K1: QKV GEMM, 128^2 tile, canonical 2-phase + FRAGMENT-READ DESWIZZLE ----------------
// R11 post-mortem: 5 sync-structure variants null -> bottleneck is the invariant: the
// [128][32] (64B-row) LDS tile makes each quad-group's ds_read_b128 hit only 8 banks
// (addr = l16*64 + quad*16). Fix per rule #21 (linear glds dest + permuted SOURCE +
// permuted READ): source chunk ^= (lane>>3)&3, read chunk ^= (l16>>1)&3. A quad-group's
// addresses r*64 + (((r>>1)&3)^q)*16 then cover all 32 banks exactly twice (2-way = free).
__global__ __launch_bounds__(256, 4) void qkv_gemm_kernel(
    const unsigned short* __restrict__ A,
    const unsigned short* __restrict__ Bw,
    const float* __restrict__ gamma, const float* __restrict__ beta,
    const float* __restrict__ mean,  const float* __restrict__ var,
    unsigned short* __restrict__ qo,   // [B,H,N,64] (pre-scaled by 0.125*log2e)
    unsigned short* __restrict__ ko,   // [B,H,N,64]
    unsigned short* __restrict__ vto)  // [B,H,256,N] with n-dim bit2<->bit3 permuted
{
  const int K = DIM;
  __shared__ unsigned short smem[17408];  // 34816B: staging 2x8192 shorts; epilogue arena aliases
  int tid = threadIdx.x;
  int wave = tid >> 6, lane = tid & 63;
  int quad = lane >> 4, l16 = lane & 15;
  int wm = wave >> 1, wn = wave & 1;
  // XCD-chunked bijective swizzle: 2352 = 8 * 294
  int bid = blockIdx.x;
  int wgid = (bid & 7) * 294 + (bid >> 3);
  int m0 = (wgid / 24) * 128, n0 = (wgid % 24) * 128;

  int srow = wave * 32 + (lane >> 2);
  int sch = ((lane & 3) ^ ((lane >> 3) & 3)) * 8;   // bank-deswizzled source chunk
  int rch = (quad ^ ((l16 >> 1) & 3)) * 8;          // matching read-side chunk
  const unsigned short* Ab = A + (size_t)(m0 + srow) * K + sch;
  const unsigned short* Bb = Bw + (size_t)(n0 + srow) * K + sch;

  floatx4 acc[4][4];
  for (int i = 0; i < 4; ++i)
    for (int j = 0; j < 4; ++j) acc[i][j] = (floatx4)0.0f;

#define STAGE_QKV(kk, buf) do {                                          \
    int off_ = ((kk) & 15) * 32;                                         \
    unsigned short* As_ = &smem[(buf) * 8192 + wave * 1024];             \
    unsigned short* Bs_ = As_ + 4096;                                    \
    glds16(Ab + off_, As_); glds16(Ab + off_ + 16 * K, As_ + 512);       \
    glds16(Bb + off_, Bs_); glds16(Bb + off_ + 16 * K, Bs_ + 512);       \
  } while (0)

  // prologue: stage k=0 -> buf0, wait, barrier
  STAGE_QKV(0, 0);
  __builtin_amdgcn_s_waitcnt(0x0F70);   // vmcnt(0)
  __builtin_amdgcn_s_barrier();

  for (int k = 0; k < 16; ++k) {
    int cur = k & 1, nb = cur ^ 1;
    STAGE_QKV((k + 1) & 15, nb);        // issue next-tile loads FIRST (wrap keeps uniform)

    const unsigned short* As = &smem[cur * 8192];
    const unsigned short* Bs = &smem[cur * 8192 + 4096];
    short8 af[4], bfr[4];
    for (int mt = 0; mt < 4; ++mt)
      af[mt] = *(const short8*)&As[(wm * 64 + mt * 16 + l16) * 32 + rch];
    for (int nt = 0; nt < 4; ++nt)
      bfr[nt] = *(const short8*)&Bs[(wn * 64 + nt * 16 + l16) * 32 + rch];
    __builtin_amdgcn_s_setprio(1);
    for (int mt = 0; mt < 4; ++mt)
      for (int nt = 0; nt < 4; ++nt)
        acc[mt][nt] = __builtin_amdgcn_mfma_f32_16x16x32_bf16(af[mt], bfr[nt], acc[mt][nt], 0, 0, 0);
    __builtin_amdgcn_s_setprio(0);

    __builtin_amdgcn_s_waitcnt(0x0F70); // vmcnt(0): next tile landed (covered by compute)
    __builtin_amdgcn_s_barrier();       // reads of cur complete (MFMA dep) -> safe to reuse
  }
#undef STAGE_QKV

  int tt = n0 % 384;        // 0 => QK tile; 128/256 => V tile
  int h = n0 / 384;
  __builtin_amdgcn_s_waitcnt(0x0070);   // belt-and-braces drain before smem reuse
  __syncthreads();

  if (tt == 0) {
    for (int nt = 0; nt < 4; ++nt) {
      int o = n0 + wn * 64 + nt * 16 + l16;
      float sc = gamma[o] * rsqrtf(var[o] + 1e-5f);
      float bb = beta[o] - mean[o] * sc;
      if (wn == 0) { sc *= 0.18033688f; bb *= 0.18033688f; }  // 0.125 * log2e folded into Q
      int jl = wn * 64 + nt * 16 + l16;
      for (int mt = 0; mt < 4; ++mt)
        for (int r = 0; r < 4; ++r) {
          int ml = wm * 64 + mt * 16 + quad * 4 + r;
          smem[ml * OSTR + jl] = f2bf(acc[mt][nt][r] * sc + bb);
        }
    }
    __syncthreads();
    for (int i = 0; i < 8; ++i) {
      int c = i * 256 + tid;
      int ml = c >> 4, jc = c & 15;
      int m = m0 + ml;
      int b = m / 784, n = m - b * 784;
      uint4 v = *(uint4*)&smem[ml * OSTR + jc * 8];
      int j = jc * 8;
      if (j < 64) *(uint4*)&qo[(((size_t)b * NH + h) * Nseq + n) * KD + j] = v;
      else        *(uint4*)&ko[(((size_t)b * NH + h) * Nseq + n) * KD + (j - 64)] = v;
    }
  } else {
    for (int nt = 0; nt < 4; ++nt) {
      int o = n0 + wn * 64 + nt * 16 + l16;
      float sc = gamma[o] * rsqrtf(var[o] + 1e-5f);
      float bb = beta[o] - mean[o] * sc;
      int cl = wn * 64 + nt * 16 + l16;
      // kv bit2<->bit3 permutation folded into the LDS write index (quad bit swap)
      int qperm = (quad & 1) * 8 + (quad >> 1) * 4;
      for (int mt = 0; mt < 4; ++mt) {
        int ml0 = wm * 64 + mt * 16 + qperm;
        ushort4 pk;
        pk.x = f2bf(acc[mt][nt][0] * sc + bb);
        pk.y = f2bf(acc[mt][nt][1] * sc + bb);
        pk.z = f2bf(acc[mt][nt][2] * sc + bb);
        pk.w = f2bf(acc[mt][nt][3] * sc + bb);
        *(ushort4*)&smem[cl * OSTR + ml0] = pk;
      }
    }
    __syncthreads();
    int cbase = tt - 128;
    for (int i = 0; i < 8; ++i) {
      int c = i * 256 + tid;
      int cl = c >> 4, mc = c & 15;
      int m = m0 + mc * 8;
      int b = m / 784, n = m - b * 784;   // n is a multiple of 8
      uint4 v = *(uint4*)&smem[cl * OSTR + mc * 8];
      *(uint4*)&vto[(((size_t)b * NH + h) * VD + cbase + cl) * Nseq + n] = v;
    }
  }
}

// ---------------- K2: flash attention, 32x32 MFMA, register-resident P ----------------
// UNCHANGED (parked at its co-saturation plateau).
__global__ __launch_bounds__(256, 2) void attn_kernel(
    const unsigned short* __restrict__ qb,   // [bh][784][64] (pre-scaled by 0.125*log2e)
    const unsigned short* __restrict__ kb,   // [bh][784][64]
    const unsigned short* __restrict__ vtb,  // [bh][256][784], n-permuted
    const unsigned short* __restrict__ bias_tab, // [8][784][784] bf16, col-permuted
    unsigned short* __restrict__ U)          // [16*784*2048] bf16 (post-SiLU)
{
  __shared__ unsigned short vt_lds[2 * 256 * 64];  // 64 KB, dbuf, swizzled
  __shared__ unsigned short k_lds[2 * 64 * 64];    // 16 KB, dbuf, swizzled
  int tid = threadIdx.x;
  int wave = tid >> 6, lane = tid & 63;
  int lo = lane & 31, hi = lane >> 5;

  int L = blockIdx.x;
  int xcd = L & 7;
  int s = L >> 3;            // 0..111
  int qp = s % 7;            // 128-row Q group
  int bg = s / 7;            // batch
  int bh = bg * 8 + xcd;     // bh % 8 == h == xcd (head-bias L2 locality)
  int b = bg, h = xcd;

  int qrow_g = qp * 128 + wave * 32 + lo;          // this lane's q row
  int qrow = qrow_g < Nseq ? qrow_g : Nseq - 1;    // clamp dead rows

  int lc = lane >> 3;              // 0..7 (row-sub for glds)
  int lch = (lane & 7) ^ lc;       // swizzled 16B chunk this lane fetches
  int swz = lo & 7;                // read-side swizzle key (== row&7 for all our reads)

  const unsigned short* vsrc = vtb + ((size_t)bh * VD + wave * 64 + lc) * Nseq + lch * 8;
  const unsigned short* ksrc = kb + ((size_t)bh * Nseq + wave * 16 + lc) * KD + lch * 8;
  const unsigned short* brow = bias_tab + (size_t)h * NN + (size_t)qrow * Nseq + 8 * hi;

  // Q fragments first (oldest vm ops)
  short8 qf[4];
  {
    const unsigned short* qp_ = qb + ((size_t)bh * Nseq + qrow) * KD + hi * 8;
#pragma unroll
    for (int kst = 0; kst < 4; ++kst) qf[kst] = *(const short8*)(qp_ + kst * 16);
  }

  // ---- prologue: issue tile 0 (10 glds) + bias tile 0 (4 tracked dwordx4) ----
#pragma unroll
  for (int i = 0; i < 8; ++i) glds16(vsrc + i * (8 * Nseq), &vt_lds[wave * 4096 + i * 512]);
  glds16(ksrc, &k_lds[wave * 1024]);
  glds16(ksrc + 8 * KD, &k_lds[wave * 1024 + 512]);
  u32x4 bbC[4], bbN[4];
#pragma unroll
  for (int g = 0; g < 4; ++g) bbC[g] = *(const u32x4*)(brow + g * 16);

  f32x16 oacc[8];
#pragma unroll
  for (int ct = 0; ct < 8; ++ct) oacc[ct] = (f32x16)0.0f;
  float lsum = 0.0f;

  for (int kt = 0; kt < 13; ++kt) {
    int cur = kt & 1, nb = cur ^ 1;
    __builtin_amdgcn_s_waitcnt(0xC07F);   // lgkmcnt(0) only
    __builtin_amdgcn_s_barrier();
    int ktn = kt + 1; if (ktn >= 13) ktn = 0;   // wrap keeps vmcnt uniform
#pragma unroll
    for (int i = 0; i < 8; ++i)
      glds16(vsrc + i * (8 * Nseq) + ktn * 64, &vt_lds[nb * 16384 + wave * 4096 + i * 512]);
    glds16(ksrc + ktn * (64 * KD), &k_lds[nb * 4096 + wave * 1024]);
    glds16(ksrc + ktn * (64 * KD) + 8 * KD, &k_lds[nb * 4096 + wave * 1024 + 512]);
    // bias for NEXT tile (tracked loads; compiler inserts its own precise wait at use)
#pragma unroll
    for (int g = 0; g < 4; ++g) bbN[g] = *(const u32x4*)(brow + ktn * 64 + g * 16);

    // S^T accumulators initialized with bias — pure reg ops on LAST tile's loads,
    // hoisted before the vmcnt+barrier so the unpack runs under the barrier wait.
    f32x16 st0, st1;
#pragma unroll
    for (int r = 0; r < 16; ++r) {
      unsigned c0 = bbC[r >> 3][(r >> 1) & 3];
      unsigned c1 = bbC[2 + (r >> 3)][(r >> 1) & 3];
      st0[r] = (r & 1) ? bfHI(c0) : bfLO(c0);
      st1[r] = (r & 1) ? bfHI(c1) : bfLO(c1);
    }

    __builtin_amdgcn_s_waitcnt(0x0F7E);   // vmcnt(14): tile kt + bias kt landed; kt+1 in flight
    __builtin_amdgcn_s_barrier();

    const unsigned short* kbuf = &k_lds[cur * 4096];
    const unsigned short* vbuf = &vt_lds[cur * 16384];

    __builtin_amdgcn_s_setprio(1);
#pragma unroll
    for (int kst = 0; kst < 4; ++kst) {
      int ch = ((kst * 2 + hi) ^ swz) * 8;
      short8 kf0 = *(const short8*)&kbuf[lo * 64 + ch];
      short8 kf1 = *(const short8*)&kbuf[(32 + lo) * 64 + ch];
      st0 = __builtin_amdgcn_mfma_f32_32x32x16_bf16(kf0, qf[kst], st0, 0, 0, 0);
      st1 = __builtin_amdgcn_mfma_f32_32x32x16_bf16(kf1, qf[kst], st1, 0, 0, 0);
    }
    __builtin_amdgcn_s_setprio(0);

    // Interleaved softmax + PV per kst-group: exp2(8) -> partial sum -> pack -> 8 MFMAs.
    bool tail = (kt == 12);
    float lp0 = 0.0f, lp1 = 0.0f, lp2 = 0.0f, lp3 = 0.0f;
#pragma unroll
    for (int kst = 0; kst < 4; ++kst) {
      float p0, p1, p2, p3, p4, p5, p6, p7;
      if (kst == 0)      { p0=st0[0]; p1=st0[1]; p2=st0[2];  p3=st0[3];  p4=st0[4];  p5=st0[5];  p6=st0[6];  p7=st0[7];  }
      else if (kst == 1) { p0=st0[8]; p1=st0[9]; p2=st0[10]; p3=st0[11]; p4=st0[12]; p5=st0[13]; p6=st0[14]; p7=st0[15]; }
      else if (kst == 2) { p0=st1[0]; p1=st1[1]; p2=st1[2];  p3=st1[3];  p4=st1[4];  p5=st1[5];  p6=st1[6];  p7=st1[7];  }
      else               { p0=st1[8]; p1=st1[9]; p2=st1[10]; p3=st1[11]; p4=st1[12]; p5=st1[13]; p6=st1[14]; p7=st1[15]; }
      p0 = EXP2(p0); p1 = EXP2(p1); p2 = EXP2(p2); p3 = EXP2(p3);
      p4 = EXP2(p4); p5 = EXP2(p5); p6 = EXP2(p6); p7 = EXP2(p7);
      if (tail && kst > 0) { p0=0; p1=0; p2=0; p3=0; p4=0; p5=0; p6=0; p7=0; }
      float ls = ((p0 + p1) + (p2 + p3)) + ((p4 + p5) + (p6 + p7));
      if (kst == 0) lp0 = ls; else if (kst == 1) lp1 = ls; else if (kst == 2) lp2 = ls; else lp3 = ls;
      unsigned X0, X1, Y0, Y1;
      asm("v_cvt_pk_bf16_f32 %0, %1, %2" : "=v"(X0) : "v"(p0), "v"(p1));
      asm("v_cvt_pk_bf16_f32 %0, %1, %2" : "=v"(X1) : "v"(p2), "v"(p3));
      asm("v_cvt_pk_bf16_f32 %0, %1, %2" : "=v"(Y0) : "v"(p4), "v"(p5));
      asm("v_cvt_pk_bf16_f32 %0, %1, %2" : "=v"(Y1) : "v"(p6), "v"(p7));
      union { unsigned u[4]; short8 s; } pk_;
      pk_.u[0] = X0; pk_.u[1] = X1; pk_.u[2] = Y0; pk_.u[3] = Y1;
      short8 pf = pk_.s;

      int ch = ((kst * 2 + hi) ^ swz) * 8;
      const unsigned short* vr0 = &vbuf[lo * 64 + ch];
      __builtin_amdgcn_s_setprio(1);
#pragma unroll
      for (int ct = 0; ct < 8; ++ct) {
        short8 vf = *(const short8*)&vr0[ct * 2048];
        oacc[ct] = __builtin_amdgcn_mfma_f32_32x32x16_bf16(vf, pf, oacc[ct], 0, 0, 0);
      }
      __builtin_amdgcn_s_setprio(0);
    }
    lsum += (lp0 + lp1) + (lp2 + lp3);

#pragma unroll
    for (int g = 0; g < 4; ++g) bbC[g] = bbN[g];
  }

  __builtin_amdgcn_s_waitcnt(0x0070);   // drain wrapped prefetch before LDS goes out of scope

  // epilogue: row sum across the two kv-halves, SiLU, write
  float tot = lsum + __shfl_xor(lsum, 32);
  float inv = 1.0f / tot;
  if (qrow_g < Nseq) {
    size_t base = ((size_t)b * Nseq + qrow_g) * HV + h * VD;
#pragma unroll
    for (int ct = 0; ct < 8; ++ct)
#pragma unroll
      for (int g2 = 0; g2 < 4; ++g2) {
        ushort4 o4;
#pragma unroll
        for (int r4 = 0; r4 < 4; ++r4) {
          float u = oacc[ct][g2 * 4 + r4] * inv;
          float sg = 1.0f / (1.0f + EXP2(-u * 1.44269504f));
          ((unsigned short*)&o4)[r4] = f2bf(u * sg);
        }
        *(ushort4*)&U[base + ct * 32 + g2 * 8 + hi * 4] = o4;
      }
  }
}

// ---------------- K3: proj GEMM, 128^2 tile, canonical 2-phase + fragment-read deswizzle ----------------
__global__ __launch_bounds__(256, 4) void proj_gemm_kernel(
    const unsigned short* __restrict__ Ubuf,  // [12544][2048]
    const unsigned short* __restrict__ Wp,    // [512][2048]
    const float* __restrict__ gamma, const float* __restrict__ beta,
    const float* __restrict__ mean,  const float* __restrict__ var,
    float* __restrict__ out)                  // [12544][512]
{
  const int K = HV;
  __shared__ unsigned short smem[16384];   // 32KB: 2 bufs x [A 4096 | B 4096] shorts
  int tid = threadIdx.x;
  int wave = tid >> 6, lane = tid & 63;
  int quad = lane >> 4, l16 = lane & 15;
  int wm = wave >> 1, wn = wave & 1;
  // XCD-chunked bijective swizzle: 392 = 8 * 49
  int bid = blockIdx.x;
  int wgid = (bid & 7) * 49 + (bid >> 3);
  int mB = (wgid % 98) * 128, o0 = (wgid / 98) * 128;

  int srow = wave * 32 + (lane >> 2);
  int sch = ((lane & 3) ^ ((lane >> 3) & 3)) * 8;   // bank-deswizzled source chunk
  int rch = (quad ^ ((l16 >> 1) & 3)) * 8;          // matching read-side chunk
  const unsigned short* Ab = Wp + (size_t)(o0 + srow) * K + sch;
  const unsigned short* Bb = Ubuf + (size_t)(mB + srow) * K + sch;

  floatx4 acc[4][4];
  for (int i = 0; i < 4; ++i)
    for (int j = 0; j < 4; ++j) acc[i][j] = (floatx4)0.0f;

#define STAGE_PROJ(kk, buf) do {                                         \
    int off_ = ((kk) & 63) * 32;                                         \
    unsigned short* As_ = &smem[(buf) * 8192 + wave * 1024];             \
    unsigned short* Bs_ = As_ + 4096;                                    \
    glds16(Ab + off_, As_); glds16(Ab + off_ + 16 * K, As_ + 512);       \
    glds16(Bb + off_, Bs_); glds16(Bb + off_ + 16 * K, Bs_ + 512);       \
  } while (0)

  STAGE_PROJ(0, 0);
  __builtin_amdgcn_s_waitcnt(0x0F70);   // vmcnt(0)
  __builtin_amdgcn_s_barrier();

  for (int k = 0; k < 64; ++k) {
    int cur = k & 1, nb = cur ^ 1;
    STAGE_PROJ((k + 1) & 63, nb);       // issue next-tile loads FIRST

    const unsigned short* As = &smem[cur * 8192];
    const unsigned short* Bs = &smem[cur * 8192 + 4096];
    short8 af[4], bfr[4];
    for (int mt = 0; mt < 4; ++mt)
      af[mt] = *(const short8*)&As[(wm * 64 + mt * 16 + l16) * 32 + rch];
    for (int nt = 0; nt < 4; ++nt)
      bfr[nt] = *(const short8*)&Bs[(wn * 64 + nt * 16 + l16) * 32 + rch];
    __builtin_amdgcn_s_setprio(1);
    for (int mt = 0; mt < 4; ++mt)
      for (int nt = 0; nt < 4; ++nt)
        acc[mt][nt] = __builtin_amdgcn_mfma_f32_16x16x32_bf16(af[mt], bfr[nt], acc[mt][nt], 0, 0, 0);
    __builtin_amdgcn_s_setprio(0);

    __builtin_amdgcn_s_waitcnt(0x0F70); // vmcnt(0): next tile landed
    __builtin_amdgcn_s_barrier();
  }
#undef STAGE_PROJ
  __builtin_amdgcn_s_waitcnt(0x0070);   // final drain (free: loop already drained)

  for (int mt = 0; mt < 4; ++mt) {
    int ob = o0 + wm * 64 + mt * 16 + quad * 4;
    float4 g = *(const float4*)&gamma[ob];
    float4 vr = *(const float4*)&var[ob];
    float4 mn = *(const float4*)&mean[ob];
    float4 bt = *(const float4*)&beta[ob];
    float sc0 = g.x * rsqrtf(vr.x + 1e-5f), bb0 = bt.x - mn.x * sc0;
    float sc1 = g.y * rsqrtf(vr.y + 1e-5f), bb1 = bt.y - mn.y * sc1;
    float sc2 = g.z * rsqrtf(vr.z + 1e-5f), bb2 = bt.z - mn.z * sc2;
    float sc3 = g.w * rsqrtf(vr.w + 1e-5f), bb3 = bt.w - mn.w * sc3;
    for (int nt = 0; nt < 4; ++nt) {
      int m = mB + wn * 64 + nt * 16 + l16;
      float4 v;
      v.x = acc[mt][nt][0] * sc0 + bb0;
      v.y = acc[mt][nt][1] * sc1 + bb1;
      v.z = acc[mt][nt][2] * sc2 + bb2;
      v.w = acc[mt][nt][3] * sc3 + bb3;
      *(float4*)&out[(size_t)m * DIM + ob] = v;
    }
  }
}

// ---------------- launch ----------------
extern "C" void kernel_launch(void* const* d_in, const int* in_sizes, int n_in,
                              void* d_out, int out_size, void* d_ws, size_t ws_size,
                              hipStream_t stream) {
  const float* x          = (const float*)d_in[0];
  const float* qkv_w      = (const float*)d_in[1];
  const float* qkv_gamma  = (const float*)d_in[2];
  const float* qkv_beta   = (const float*)d_in[3];
  const float* qkv_mean   = (const float*)d_in[4];
  const float* qkv_var    = (const float*)d_in[5];
  const float* att_biases = (const float*)d_in[6];
  const float* proj_w     = (const float*)d_in[7];
  const float* proj_gamma = (const float*)d_in[8];
  const float* proj_beta  = (const float*)d_in[9];
  const float* proj_mean  = (const float*)d_in[10];
  const float* proj_var   = (const float*)d_in[11];
  const int*   bias_idxs  = (const int*)d_in[12];
  float* out = (float*)d_out;

  char* ws = (char*)d_ws;
  unsigned short* xb  = (unsigned short*)(ws);                 // 12544*512 (12.85 MB)
  unsigned short* bias_tab = (unsigned short*)(ws);            // 8*784*784 bf16 — aliases xb (dead after qkv_gemm)
  unsigned short* wq  = (unsigned short*)(ws + 12845056);      // 3072*512
  unsigned short* wp  = (unsigned short*)(ws + 15990784);      // 512*2048
  unsigned short* qo  = (unsigned short*)(ws + 18087936);      // 16*8*784*64
  unsigned short* ko  = (unsigned short*)(ws + 30932992);      // 16*8*784*64
  unsigned short* vto = (unsigned short*)(ws + 43778048);      // 16*8*256*784
  unsigned short* Ub  = (unsigned short*)(ws + 95158272);      // 12544*2048
  // total: 146538496 bytes

  {
    int n4 = N4X + N4Q + N4P;
    cvt_all_kernel<<<(n4 + 255) / 256, 256, 0, stream>>>(x, qkv_w, proj_w, xb, wq, wp);
  }

  qkv_gemm_kernel<<<2352, 256, 0, stream>>>(
      xb, wq, qkv_gamma, qkv_beta, qkv_mean, qkv_var, qo, ko, vto);

  bias_pre_kernel<<<(NN + 255) / 256, 256, 0, stream>>>(att_biases, bias_idxs, bias_tab);

  attn_kernel<<<7 * Bsz * NH, 256, 0, stream>>>(qo, ko, vto, bias_tab, Ub);

  proj_gemm_kernel<<<392, 256, 0, stream>>>(
      Ub, wp, proj_gamma, proj_beta, proj_mean, proj_var, out);
}